// Round 8
// baseline (525.332 us; speedup 1.0000x reference)
//
#include <hip/hip_runtime.h>
#include <hip/hip_bf16.h>

typedef __attribute__((ext_vector_type(8))) short short8;
typedef __attribute__((ext_vector_type(4))) short short4v;
typedef __attribute__((ext_vector_type(4))) float floatx4;

#define TDIM 2048
#define BDIM 2
#define MROWS (BDIM * TDIM)   // 4096

#define ASM_VMCNT0() __asm__ volatile("s_waitcnt vmcnt(0)" ::: "memory")
#define ASM_VMCNT2() __asm__ volatile("s_waitcnt vmcnt(2)" ::: "memory")
#define ASM_VMCNT4() __asm__ volatile("s_waitcnt vmcnt(4)" ::: "memory")
#define ASM_LGKM0()  __asm__ volatile("s_waitcnt lgkmcnt(0)" ::: "memory")
#define ASM_BARRIER() __asm__ volatile("s_barrier" ::: "memory")

// K=16 bf16 MFMA wrapper (device pass picks the real builtin).
__device__ __forceinline__ floatx4 mfma16(short4v a, short4v b, floatx4 c) {
#if defined(__HIP_DEVICE_COMPILE__)
#if __has_builtin(__builtin_amdgcn_mfma_f32_16x16x16bf16_1k)
    return __builtin_amdgcn_mfma_f32_16x16x16bf16_1k(a, b, c, 0, 0, 0);
#else
    short8 az = {a[0], a[1], a[2], a[3], 0, 0, 0, 0};
    short8 bz = {b[0], b[1], b[2], b[3], 0, 0, 0, 0};
    return __builtin_amdgcn_mfma_f32_16x16x32_bf16(az, bz, c, 0, 0, 0);
#endif
#else
    (void)a; (void)b;
    return c;
#endif
}

// async global->LDS, 16B per lane; LDS dest = wave-uniform base + lane*16
__device__ __forceinline__ void gload_lds16(const void* g, void* l) {
    __builtin_amdgcn_global_load_lds((const __attribute__((address_space(1))) void*)g,
                                     (__attribute__((address_space(3))) void*)l, 16, 0, 0);
}

__device__ __forceinline__ short bf16s(float x) {
    __hip_bfloat16 h = __float2bfloat16(x);
    return *(short*)&h;
}

// native 2^x through the COMPILER (hazard-safe), not inline asm
__device__ __forceinline__ float fexp2(float x) {
#if defined(__HIP_DEVICE_COMPILE__)
#if __has_builtin(__builtin_amdgcn_exp2f)
    return __builtin_amdgcn_exp2f(x);
#else
    return exp2f(x);
#endif
#else
    return x;
#endif
}

// ---------------------------------------------------------------------------
// fused dual cast fp32 -> bf16 (dec then enc), 4 elems/thread
__global__ __launch_bounds__(256) void cast2_k(const float* __restrict__ a,
                                               const float* __restrict__ b,
                                               __hip_bfloat16* __restrict__ oa,
                                               __hip_bfloat16* __restrict__ ob) {
    const int blk = blockIdx.x;
    const float* in = (blk < 4096) ? a : b;
    __hip_bfloat16* out = (blk < 4096) ? oa : ob;
    const size_t base = (size_t)(blk & 4095) * 1024 + threadIdx.x * 4;
    float4 v = *(const float4*)&in[base];
    out[base + 0] = __float2bfloat16(v.x);
    out[base + 1] = __float2bfloat16(v.y);
    out[base + 2] = __float2bfloat16(v.z);
    out[base + 3] = __float2bfloat16(v.w);
}

// 32x32 transpose-cast tile helper
__device__ __forceinline__ void t32(float (*tile)[33], const float* __restrict__ in,
                                    __hip_bfloat16* __restrict__ out, int R, int C,
                                    int c0, int r0) {
    const int tx = threadIdx.x & 31, ty = threadIdx.x >> 5;
#pragma unroll
    for (int i = 0; i < 4; ++i)
        tile[ty + 8 * i][tx] = in[(size_t)(r0 + ty + 8 * i) * C + c0 + tx];
    __syncthreads();
#pragma unroll
    for (int i = 0; i < 4; ++i)
        out[(size_t)(c0 + ty + 8 * i) * R + r0 + tx] = __float2bfloat16(tile[tx][ty + 8 * i]);
}

// One fused kernel for ALL weight prep: 10 transposes + 2 bias concats.
__global__ __launch_bounds__(256) void prep_w_k(
    const float* __restrict__ Wq_s, const float* __restrict__ Wk_s, const float* __restrict__ Wv_s,
    const float* __restrict__ Wq_c, const float* __restrict__ Wk_c, const float* __restrict__ Wv_c,
    const float* __restrict__ Wo_s, const float* __restrict__ Wo_c,
    const float* __restrict__ W1, const float* __restrict__ W2,
    const float* __restrict__ bq_s, const float* __restrict__ bk_s, const float* __restrict__ bv_s,
    const float* __restrict__ bk_c, const float* __restrict__ bv_c,
    __hip_bfloat16* __restrict__ WtQKVs, __hip_bfloat16* __restrict__ WtQc,
    __hip_bfloat16* __restrict__ WtKVc, __hip_bfloat16* __restrict__ WtOs,
    __hip_bfloat16* __restrict__ WtOc, __hip_bfloat16* __restrict__ Wt1,
    __hip_bfloat16* __restrict__ Wt2,
    float* __restrict__ BiasQKVs, float* __restrict__ BiasKVc) {
    __shared__ float tile[32][33];
    const int t = blockIdx.x;
    if (t < 6144) {  // per-head stacks: R=1024, C=64, 16 slabs, 64 tiles/slab
        const int seg = t >> 10, tl = t & 1023;
        const float* s;
        __hip_bfloat16* d;
        if (seg == 0) { s = Wq_s; d = WtQKVs; }
        else if (seg == 1) { s = Wk_s; d = WtQKVs + 1048576; }
        else if (seg == 2) { s = Wv_s; d = WtQKVs + 2097152; }
        else if (seg == 3) { s = Wq_c; d = WtQc; }
        else if (seg == 4) { s = Wk_c; d = WtKVc; }
        else { s = Wv_c; d = WtKVc + 1048576; }
        const int slab = tl >> 6, rem = tl & 63;
        t32(tile, s + (size_t)slab * 65536, d + (size_t)slab * 65536, 1024, 64,
            (rem & 1) * 32, (rem >> 1) * 32);
    } else if (t < 8192) {  // Wo_s / Wo_c: 1024x1024
        const int rem = (t - 6144) & 1023;
        const float* s = (t < 7168) ? Wo_s : Wo_c;
        __hip_bfloat16* d = (t < 7168) ? WtOs : WtOc;
        t32(tile, s, d, 1024, 1024, (rem & 31) * 32, (rem >> 5) * 32);
    } else if (t < 12288) {  // W1: R=1024 C=4096
        const int rem = t - 8192;
        t32(tile, W1, Wt1, 1024, 4096, (rem & 127) * 32, (rem >> 7) * 32);
    } else if (t < 16384) {  // W2: R=4096 C=1024
        const int rem = t - 12288;
        t32(tile, W2, Wt2, 4096, 1024, (rem & 31) * 32, (rem >> 5) * 32);
    } else if (t < 16396) {  // concat3 -> BiasQKVs
        const int i = (t - 16384) * 256 + threadIdx.x;
        BiasQKVs[i] = (i < 1024) ? bq_s[i] : (i < 2048 ? bk_s[i - 1024] : bv_s[i - 2048]);
    } else {  // concat2 -> BiasKVc
        const int i = (t - 16396) * 256 + threadIdx.x;
        BiasKVc[i] = (i < 1024) ? bk_c[i] : bv_c[i - 1024];
    }
}

// ---------------------------------------------------------------------------
// 128x128 4-wave GEMM core (kept for small split-K Wo GEMMs).
__device__ __forceinline__ void gemm_core(
    const __hip_bfloat16* __restrict__ A, const __hip_bfloat16* __restrict__ Bt,
    int K, int kBeg, int kLen,
    const float* __restrict__ bias, __hip_bfloat16* __restrict__ C, int ldc,
    float* __restrict__ Pf,
    __hip_bfloat16* __restrict__ Vt, int vt_col0, int relu,
    int m0, int n0, __hip_bfloat16* sm) {
    const int tid = threadIdx.x;
    const int lane = tid & 63, wave = tid >> 6;
    const int quad = lane >> 4, l16 = lane & 15;
    const int wm = (wave >> 1) * 64, wn = (wave & 1) * 64;
    const int lrow = lane >> 3;
    const int gsw = (((lane & 7) ^ lrow)) * 8;  // swizzled source column (elems)
    const int sw7 = l16 & 7;                    // reader swizzle key (row&7)
    const __hip_bfloat16* gA = A + (size_t)(m0 + wave * 32 + lrow) * K + kBeg + gsw;
    const __hip_bfloat16* gB = Bt + (size_t)(n0 + wave * 32 + lrow) * K + kBeg + gsw;
    __hip_bfloat16* lA = sm + wave * 2048;
    __hip_bfloat16* lB = sm + 16384 + wave * 2048;
    floatx4 acc[4][4] = {};
    const int T = kLen >> 6;
#pragma unroll
    for (int i = 0; i < 4; ++i) {
        gload_lds16(gA + (size_t)i * 8 * K, lA + i * 512);
        gload_lds16(gB + (size_t)i * 8 * K, lB + i * 512);
    }
    for (int t = 0; t < T; ++t) {
        ASM_VMCNT0();
        ASM_BARRIER();
        if (t + 1 < T) {
            const int koff = (t + 1) << 6;
            const int b = ((t + 1) & 1) * 8192;
#pragma unroll
            for (int i = 0; i < 4; ++i) {
                gload_lds16(gA + (size_t)i * 8 * K + koff, lA + b + i * 512);
                gload_lds16(gB + (size_t)i * 8 * K + koff, lB + b + i * 512);
            }
        }
        const __hip_bfloat16* cA = sm + (t & 1) * 8192;
        const __hip_bfloat16* cB = sm + 16384 + (t & 1) * 8192;
#pragma unroll
        for (int kc = 0; kc < 2; ++kc) {
            short8 af[4], bfr[4];
#pragma unroll
            for (int i = 0; i < 4; ++i) {
                af[i] = *(const short8*)&cA[(wm + i * 16 + l16) * 64 +
                                            (((kc * 4 + quad) ^ sw7) * 8)];
                bfr[i] = *(const short8*)&cB[(wn + i * 16 + l16) * 64 +
                                             (((kc * 4 + quad) ^ sw7) * 8)];
            }
#pragma unroll
            for (int mi = 0; mi < 4; ++mi)
#pragma unroll
                for (int ni = 0; ni < 4; ++ni)
                    acc[mi][ni] =
                        __builtin_amdgcn_mfma_f32_16x16x32_bf16(af[mi], bfr[ni], acc[mi][ni], 0, 0, 0);
        }
    }
    // epilogue
    if (Pf) {
#pragma unroll
        for (int ni = 0; ni < 4; ++ni) {
            const int col = n0 + wn + ni * 16 + l16;
#pragma unroll
            for (int mi = 0; mi < 4; ++mi)
#pragma unroll
                for (int r = 0; r < 4; ++r) {
                    const int row = m0 + wm + mi * 16 + quad * 4 + r;
                    Pf[(size_t)row * ldc + col] = acc[mi][ni][r];
                }
        }
    } else {
        const bool toVt = (n0 >= vt_col0);
#pragma unroll
        for (int ni = 0; ni < 4; ++ni) {
            const int col = n0 + wn + ni * 16 + l16;
            const float bv = bias[col];
#pragma unroll
            for (int mi = 0; mi < 4; ++mi) {
                const int row0 = m0 + wm + mi * 16 + quad * 4;
                if (toVt) {
                    const int b = row0 >> 11, t0 = row0 & (TDIM - 1);
                    short4v pk;
#pragma unroll
                    for (int r = 0; r < 4; ++r) pk[r] = bf16s(acc[mi][ni][r] + bv);
                    *(short4v*)&Vt[((size_t)(b * 1024 + (col - vt_col0)) << 11) + t0] = pk;
                } else {
#pragma unroll
                    for (int r = 0; r < 4; ++r) {
                        float v = acc[mi][ni][r] + bv;
                        if (relu) v = fmaxf(v, 0.f);
                        C[(size_t)(row0 + r) * ldc + col] = __float2bfloat16(v);
                    }
                }
            }
        }
    }
}

__global__ __launch_bounds__(256) void gemm_sk2_k(const __hip_bfloat16* __restrict__ A,
                                                  const __hip_bfloat16* __restrict__ Bt,
                                                  float* __restrict__ Pf, int N, int K) {
    __shared__ __hip_bfloat16 sm[2 * 128 * 64 * 2];
    const int z = blockIdx.z;
    gemm_core(A, Bt, K, z * (K >> 1), K >> 1, nullptr, nullptr, N,
              Pf + (size_t)z * MROWS * N, nullptr, 1 << 30, 0,
              blockIdx.y * 128, blockIdx.x * 128, sm);
}

// ---------------------------------------------------------------------------
// 256x256 8-wave GEMM core, deep-prefetch double-buffer: ALL 8 next-step DMAs
// are issued immediately after the top barrier (one full K-step of latency
// hiding), computed step runs barrier-free, one vmcnt(0)+barrier per step.
// Same g^(row&7) granule swizzle (pre-swizzled source, linear DMA dest, XOR
// on read). LDS 128 KiB -> 1 WG/CU.
__device__ __forceinline__ void gemm256_core(
    const __hip_bfloat16* __restrict__ A, const __hip_bfloat16* __restrict__ Bt,
    int K, int kBeg, int kLen,
    const float* __restrict__ bias, __hip_bfloat16* __restrict__ C, int ldc,
    float* __restrict__ Pf,
    __hip_bfloat16* __restrict__ Vt, int vt_col0, int relu,
    int m0, int n0, __hip_bfloat16* sm) {
    const int tid = threadIdx.x;
    const int lane = tid & 63, wave = tid >> 6;
    const int quad = lane >> 4, l16 = lane & 15;
    const int wm = (wave >> 2) * 128, wn = (wave & 3) * 64;
    const int lrow = lane >> 3;
    const int gsw = ((lane & 7) ^ lrow) * 8;
    const int sw7 = l16 & 7;
    const __hip_bfloat16* aSrc = A + (size_t)(m0 + wave * 16 + lrow) * K + kBeg + gsw;
    const __hip_bfloat16* bSrc = Bt + (size_t)(n0 + wave * 16 + lrow) * K + kBeg + gsw;
    floatx4 acc[8][4] = {};
    const int T = kLen >> 6;
    // prologue: stage K-step 0 into buf0 (8 DMAs/wave)
#pragma unroll
    for (int h = 0; h < 2; ++h)
#pragma unroll
        for (int j = 0; j < 2; ++j) {
            const size_t ro = (size_t)(h * 128 + j * 8);
            gload_lds16(aSrc + ro * K, sm + (h * 128 + wave * 16 + j * 8) * 64);
            gload_lds16(bSrc + ro * K, sm + 16384 + (h * 128 + wave * 16 + j * 8) * 64);
        }
    for (int t = 0; t < T; ++t) {
        const int c = t & 1;
        const __hip_bfloat16* cA = sm + c * 32768;
        const __hip_bfloat16* cB = cA + 16384;
        ASM_VMCNT0();   // own step-t DMAs complete (only outstanding vmem)
        ASM_BARRIER();  // ALL waves' step-t DMAs complete
        if (t + 1 < T) {  // issue all 8 next-step DMAs NOW (full-step distance)
            __hip_bfloat16* dst = sm + (1 - c) * 32768;
            const size_t nko = (size_t)(t + 1) * 64;
#pragma unroll
            for (int h = 0; h < 2; ++h)
#pragma unroll
                for (int j = 0; j < 2; ++j) {
                    const size_t ro = (size_t)(h * 128 + j * 8);
                    gload_lds16(aSrc + ro * K + nko, dst + (h * 128 + wave * 16 + j * 8) * 64);
                    gload_lds16(bSrc + ro * K + nko, dst + 16384 + (h * 128 + wave * 16 + j * 8) * 64);
                }
        }
#pragma unroll
        for (int kh = 0; kh < 2; ++kh) {
            const int gk = ((kh * 4 + quad) ^ sw7) * 8;
            short8 af[4], bfr[4];
#pragma unroll
            for (int i = 0; i < 4; ++i) {
                af[i] = *(const short8*)&cA[(wm + i * 16 + l16) * 64 + gk];
                bfr[i] = *(const short8*)&cB[(wn + i * 16 + l16) * 64 + gk];
            }
            __builtin_amdgcn_s_setprio(1);
#pragma unroll
            for (int mi = 0; mi < 4; ++mi)
#pragma unroll
                for (int ni = 0; ni < 4; ++ni)
                    acc[mi][ni] = __builtin_amdgcn_mfma_f32_16x16x32_bf16(af[mi], bfr[ni], acc[mi][ni], 0, 0, 0);
            __builtin_amdgcn_s_setprio(0);
#pragma unroll
            for (int i = 0; i < 4; ++i)
                af[i] = *(const short8*)&cA[(wm + 64 + i * 16 + l16) * 64 + gk];
            __builtin_amdgcn_s_setprio(1);
#pragma unroll
            for (int mi = 0; mi < 4; ++mi)
#pragma unroll
                for (int ni = 0; ni < 4; ++ni)
                    acc[4 + mi][ni] = __builtin_amdgcn_mfma_f32_16x16x32_bf16(af[mi], bfr[ni], acc[4 + mi][ni], 0, 0, 0);
            __builtin_amdgcn_s_setprio(0);
        }
    }
    // epilogue (same formulas as gemm_core, mi now 0..7)
    if (Pf) {
#pragma unroll
        for (int ni = 0; ni < 4; ++ni) {
            const int col = n0 + wn + ni * 16 + l16;
#pragma unroll
            for (int mi = 0; mi < 8; ++mi)
#pragma unroll
                for (int r = 0; r < 4; ++r) {
                    const int row = m0 + wm + mi * 16 + quad * 4 + r;
                    Pf[(size_t)row * ldc + col] = acc[mi][ni][r];
                }
        }
    } else {
        const bool toVt = (n0 >= vt_col0);
#pragma unroll
        for (int ni = 0; ni < 4; ++ni) {
            const int col = n0 + wn + ni * 16 + l16;
            const float bv = bias[col];
#pragma unroll
            for (int mi = 0; mi < 8; ++mi) {
                const int row0 = m0 + wm + mi * 16 + quad * 4;
                if (toVt) {
                    const int b = row0 >> 11, t0 = row0 & (TDIM - 1);
                    short4v pk;
#pragma unroll
                    for (int r = 0; r < 4; ++r) pk[r] = bf16s(acc[mi][ni][r] + bv);
                    *(short4v*)&Vt[((size_t)(b * 1024 + (col - vt_col0)) << 11) + t0] = pk;
                } else {
#pragma unroll
                    for (int r = 0; r < 4; ++r) {
                        float v = acc[mi][ni][r] + bv;
                        if (relu) v = fmaxf(v, 0.f);
                        C[(size_t)(row0 + r) * ldc + col] = __float2bfloat16(v);
                    }
                }
            }
        }
    }
}

__global__ __launch_bounds__(512, 2) void g256_k(const __hip_bfloat16* __restrict__ A,
                                                 const __hip_bfloat16* __restrict__ Bt,
                                                 const float* __restrict__ bias,
                                                 __hip_bfloat16* __restrict__ C,
                                                 int N, int K, int relu,
                                                 __hip_bfloat16* __restrict__ Vt, int vt_col0) {
    __shared__ __hip_bfloat16 sm[65536];  // 128 KiB
    gemm256_core(A, Bt, K, 0, K, bias, C, N, nullptr, Vt, vt_col0, relu,
                 blockIdx.y * 256, blockIdx.x * 256, sm);
}

// FFN2 split-K 4: 4 f32 partial outputs (combined by ln4_k). 256 blocks.
__global__ __launch_bounds__(512, 2) void g256_sk4_k(const __hip_bfloat16* __restrict__ A,
                                                     const __hip_bfloat16* __restrict__ Bt,
                                                     float* __restrict__ Pf0, float* __restrict__ Pf1,
                                                     float* __restrict__ Pf2, float* __restrict__ Pf3,
                                                     int N, int K) {
    __shared__ __hip_bfloat16 sm[65536];
    const int z = blockIdx.z;
    float* pf = (z == 0) ? Pf0 : (z == 1) ? Pf1 : (z == 2) ? Pf2 : Pf3;
    gemm256_core(A, Bt, K, z * (K >> 2), K >> 2, nullptr, nullptr, N, pf,
                 nullptr, 1 << 30, 0, blockIdx.y * 256, blockIdx.x * 256, sm);
}

__global__ __launch_bounds__(512, 2) void g256_pair_k(
    const __hip_bfloat16* __restrict__ A1, const __hip_bfloat16* __restrict__ Bt1,
    const float* __restrict__ bias1, __hip_bfloat16* __restrict__ C1, int N1, int K1,
    const __hip_bfloat16* __restrict__ A2, const __hip_bfloat16* __restrict__ Bt2,
    const float* __restrict__ bias2, __hip_bfloat16* __restrict__ C2, int N2, int K2,
    __hip_bfloat16* __restrict__ Vt2, int vtc2, int nx1) {
    __shared__ __hip_bfloat16 sm[65536];
    if ((int)blockIdx.x < nx1)
        gemm256_core(A1, Bt1, K1, 0, K1, bias1, C1, N1, nullptr, nullptr, 1 << 30, 0,
                     blockIdx.y * 256, blockIdx.x * 256, sm);
    else
        gemm256_core(A2, Bt2, K2, 0, K2, bias2, C2, N2, nullptr, Vt2, vtc2, 0,
                     blockIdx.y * 256, (blockIdx.x - nx1) * 256, sm);
}

// ---------------------------------------------------------------------------
// Flash attention, register-resident P. Processes k-tiles [tBeg, tEnd).
// k-loop unrolled x2 so the LDS double-buffer offset (CB/NB) is a literal
// (ds_read offset-immediate folding). Split K/V waits: per wave DMAs are
// issued K,K,V,V; tile top waits vmcnt(2) (K ready, V in flight), QK^T+exp
// overlap V arrival; vmcnt(4) before PV (V ready, next tile's 4 prefetch
// DMAs stay in flight). Invariant: exactly 4 DMAs outstanding at tile top
// (last tile re-stages itself to keep counts uniform).
__device__ __forceinline__ void flash_one(
    const __hip_bfloat16* __restrict__ Q, int ldq, int qc0,
    const __hip_bfloat16* __restrict__ Kp, int ldk,
    const __hip_bfloat16* __restrict__ Vp,
    __hip_bfloat16* __restrict__ O, int causal, int q0, size_t rowb, int h,
    int tBeg, int tEnd, float* __restrict__ Opart, float* __restrict__ lpart,
    __hip_bfloat16* sK, __hip_bfloat16* sV) {
    const int tid = threadIdx.x, lane = tid & 63, wave = tid >> 6;
    const int quad = lane >> 4, l16 = lane & 15;
    const int lrow = lane >> 3;
    const int gsw = ((lane & 7) ^ lrow) * 8;  // DMA swizzled source col (elems)
    const int sw7 = l16 & 7;
    short8 qf[2];
    {
        const __hip_bfloat16* qp = Q + (rowb + q0 + wave * 16 + l16) * (size_t)ldq + qc0 + h * 64;
        const float qs = 0.18033688f;  // 0.125 * log2(e)
        short8 r0 = *(const short8*)(qp + quad * 8);
        short8 r1 = *(const short8*)(qp + 32 + quad * 8);
#pragma unroll
        for (int j = 0; j < 8; ++j) {
            qf[0][j] = bf16s(__uint_as_float(((unsigned)(unsigned short)r0[j]) << 16) * qs);
            qf[1][j] = bf16s(__uint_as_float(((unsigned)(unsigned short)r1[j]) << 16) * qs);
        }
    }
    short4v ones4;
#pragma unroll
    for (int j = 0; j < 4; ++j) ones4[j] = (short)0x3F80;  // bf16 1.0
    floatx4 Ot[4] = {};  // Ot[dt][r] = O[q=..+l16][d=dt*16+quad*4+r]
    floatx4 accl = {};
    const int nDiag = q0 >> 6;
    const int rb = wave * 16;
    ASM_LGKM0();
    ASM_BARRIER();
    {   // prologue stage: K,K then V,V (order matters for counted waits)
        const int s0 = tBeg << 6, pb = (tBeg & 1) * 4096;
        gload_lds16(&Kp[(rowb + s0 + rb + lrow) * (size_t)ldk + gsw], &sK[pb + rb * 64]);
        gload_lds16(&Kp[(rowb + s0 + rb + 8 + lrow) * (size_t)ldk + gsw], &sK[pb + (rb + 8) * 64]);
        gload_lds16(&Vp[(size_t)(rb + lrow) * TDIM + s0 + gsw], &sV[pb + rb * 64]);
        gload_lds16(&Vp[(size_t)(rb + 8 + lrow) * TDIM + s0 + gsw], &sV[pb + (rb + 8) * 64]);
    }

#define FA_TILE(TT, CB, NB)                                                              \
    do {                                                                                 \
        const int tt = (TT);                                                             \
        ASM_VMCNT2();  /* this tile's K landed (V may still be in flight) */             \
        ASM_BARRIER();                                                                   \
        {   /* prefetch next tile (clamped on last -> uniform wait counts) */            \
            const int nx = (tt + 1 < tEnd) ? tt + 1 : tt;                                \
            const int s1 = nx << 6;                                                      \
            gload_lds16(&Kp[(rowb + s1 + rb + lrow) * (size_t)ldk + gsw],                \
                        &sK[(NB) + rb * 64]);                                            \
            gload_lds16(&Kp[(rowb + s1 + rb + 8 + lrow) * (size_t)ldk + gsw],            \
                        &sK[(NB) + (rb + 8) * 64]);                                      \
            gload_lds16(&Vp[(size_t)(rb + lrow) * TDIM + s1 + gsw],                      \
                        &sV[(NB) + rb * 64]);                                            \
            gload_lds16(&Vp[(size_t)(rb + 8 + lrow) * TDIM + s1 + gsw],                  \
                        &sV[(NB) + (rb + 8) * 64]);                                      \
        }                                                                                \
        floatx4 Sf[4] = {};                                                              \
        _Pragma("unroll") for (int st = 0; st < 4; ++st) {                               \
            short8 b0 = *(const short8*)&sK[(CB) + (st * 16 + l16) * 64 +                \
                                            ((quad ^ sw7) * 8)];                         \
            short8 b1 = *(const short8*)&sK[(CB) + (st * 16 + l16) * 64 +                \
                                            (((4 + quad) ^ sw7) * 8)];                   \
            Sf[st] = __builtin_amdgcn_mfma_f32_16x16x32_bf16(b0, qf[0], Sf[st], 0, 0, 0);\
            Sf[st] = __builtin_amdgcn_mfma_f32_16x16x32_bf16(b1, qf[1], Sf[st], 0, 0, 0);\
        }                                                                                \
        _Pragma("unroll") for (int st = 0; st < 4; ++st)                                 \
            _Pragma("unroll") for (int r = 0; r < 4; ++r) Sf[st][r] = fexp2(Sf[st][r]);  \
        if (causal && tt == nDiag) {                                                     \
            const int qr = wave * 16 + l16;                                              \
            _Pragma("unroll") for (int st = 0; st < 4; ++st)                             \
                _Pragma("unroll") for (int r = 0; r < 4; ++r)                            \
                    if (st * 16 + quad * 4 + r > qr) Sf[st][r] = 0.f;                    \
        }                                                                                \
        short4v pf[4];                                                                   \
        _Pragma("unroll") for (int st = 0; st < 4; ++st)                                 \
            _Pragma("unroll") for (int r = 0; r < 4; ++r) pf[st][r] = bf16s(Sf[st][r]);  \
        ASM_VMCNT4();  /* this tile's V landed (next tile's 4 DMAs in flight) */         \
        ASM_BARRIER();                                                                   \
        _Pragma("unroll") for (int st = 0; st < 4; ++st) accl = mfma16(ones4, pf[st], accl); \
        _Pragma("unroll") for (int dt = 0; dt < 4; ++dt)                                 \
            _Pragma("unroll") for (int st = 0; st < 4; ++st) {                           \
                short4v av = *(const short4v*)&sV[(CB) + (dt * 16 + l16) * 64 +          \
                                                 (((st * 2 + (quad >> 1)) ^ sw7) * 8) +  \
                                                 (quad & 1) * 4];                        \
                Ot[dt] = mfma16(av, pf[st], Ot[dt]);                                     \
            }                                                                            \
    } while (0)

    int t = tBeg;
    if (t & 1) { FA_TILE(t, 4096, 0); ++t; }
    for (; t + 1 < tEnd; t += 2) {
        FA_TILE(t, 0, 4096);
        FA_TILE(t + 1, 4096, 0);
    }
    if (t < tEnd) FA_TILE(t, 0, 4096);
#undef FA_TILE

    if (Opart) {
        const int qrow = wave * 16 + l16;
#pragma unroll
        for (int dt = 0; dt < 4; ++dt)
            *(floatx4*)&Opart[qrow * 64 + dt * 16 + quad * 4] = Ot[dt];
        if (quad == 0) lpart[qrow] = accl[0];
    } else {
        const float inv = 1.0f / accl[0];
        __hip_bfloat16* op = O + (rowb + q0 + wave * 16 + l16) * (size_t)1024 + h * 64 + quad * 4;
#pragma unroll
        for (int dt = 0; dt < 4; ++dt) {
            short4v pk;
#pragma unroll
            for (int r = 0; r < 4; ++r) pk[r] = bf16s(Ot[dt][r] * inv);
            *(short4v*)(op + dt * 16) = pk;
        }
    }
}

// XCD-aware remap (T1): all q-blocks of one (b,h) land on one XCD so its
// K/V head is fetched into that XCD's L2 exactly once. Linear wgid w:
// bh = (w&7)*4 + ((w>>3)&3), bx = w>>5. Bijective for gy=32, gx in {32,48,64}.
// causal=1: grid (48,32):
//   bx 0..31  -> q-tiles i=16+(bx>>1) split into half k-ranges hh=bx&1 (partials)
//   bx 32..47 -> q-tiles i=47-bx unsplit (direct output)
// causal=0 + Opart: grid (64,32): q-tile i=bx>>1, half k-range hh=bx&1 (partials)
__global__ __launch_bounds__(256) void flash_attn(const __hip_bfloat16* __restrict__ Q, int ldq, int qc0,
                                                  const __hip_bfloat16* __restrict__ K, int ldk, int kc0,
                                                  const __hip_bfloat16* __restrict__ Vt,
                                                  __hip_bfloat16* __restrict__ O, int causal,
                                                  float* __restrict__ Opart,
                                                  float* __restrict__ lpart) {
    __shared__ __hip_bfloat16 sK[2 * 64 * 64];
    __shared__ __hip_bfloat16 sV[2 * 64 * 64];
    const int w = (int)blockIdx.y * (int)gridDim.x + (int)blockIdx.x;
    const int bh = (w & 7) * 4 + ((w >> 3) & 3);
    const int bx = w >> 5;
    const int b = bh >> 4, h = bh & 15;
    const size_t rowb = (size_t)b * TDIM;
    const __hip_bfloat16* Kp = K + kc0 + h * 64;
    const __hip_bfloat16* Vp = Vt + ((size_t)(b * 1024 + h * 64) << 11);
    if (causal) {
        if (bx < 32) {
            const int i = 16 + (bx >> 1), hh = bx & 1;
            const int n = i + 1, n2 = n >> 1;
            const int p = bh * 16 + (i - 16);
            float* Op = Opart + (size_t)p * 8192 + hh * 4096;
            float* lp = lpart + p * 128 + hh * 64;
            flash_one(Q, ldq, qc0, Kp, ldk, Vp, O, 1, i * 64, rowb, h,
                      hh ? n2 : 0, hh ? n : n2, Op, lp, sK, sV);
        } else {
            const int i = 47 - bx;
            flash_one(Q, ldq, qc0, Kp, ldk, Vp, O, 1, i * 64, rowb, h,
                      0, i + 1, nullptr, nullptr, sK, sV);
        }
    } else if (Opart) {
        const int i = bx >> 1, hh = bx & 1;
        const int p = bh * 32 + i;
        float* Op = Opart + (size_t)p * 8192 + hh * 4096;
        float* lp = lpart + p * 128 + hh * 64;
        flash_one(Q, ldq, qc0, Kp, ldk, Vp, O, 0, i * 64, rowb, h,
                  hh ? 16 : 0, hh ? 32 : 16, Op, lp, sK, sV);
    } else {
        flash_one(Q, ldq, qc0, Kp, ldk, Vp, O, 0, bx * 64, rowb, h,
                  0, TDIM >> 6, nullptr, nullptr, sK, sV);
    }
}

// combine split-k flash partials: O = (O0+O1)/(l0+l1).
// p = bh*(1<<shift) + (i - ibase); causal: shift=4 ibase=16; cross: shift=5 ibase=0.
__global__ __launch_bounds__(256) void fa_combine_k(const float* __restrict__ Opart,
                                                    const float* __restrict__ lpart,
                                                    __hip_bfloat16* __restrict__ O,
                                                    int shift, int ibase) {
    const int p = blockIdx.x;
    const int bh = p >> shift, i = (p & ((1 << shift) - 1)) + ibase;
    const int b = bh >> 4, h = bh & 15;
    const int tid = threadIdx.x;
    const int q = tid >> 2, dseg = (tid & 3) * 16;
    const float* O0 = Opart + (size_t)p * 8192;
    const float* O1 = O0 + 4096;
    const float inv = 1.f / (lpart[p * 128 + q] + lpart[p * 128 + 64 + q]);
    __hip_bfloat16* op = O + ((size_t)(b * TDIM) + i * 64 + q) * 1024 + h * 64 + dseg;
#pragma unroll
    for (int j = 0; j < 4; ++j) {
        floatx4 a = *(const floatx4*)&O0[q * 64 + dseg + j * 4];
        floatx4 c = *(const floatx4*)&O1[q * 64 + dseg + j * 4];
        short4v pk;
#pragma unroll
        for (int r = 0; r < 4; ++r) pk[r] = bf16s((a[r] + c[r]) * inv);
        *(short4v*)(op + j * 4) = pk;
    }
}

// ---------------------------------------------------------------------------
// LayerNorm with fused split-K reduction: delta = d0 + d1 + biasN.
__global__ __launch_bounds__(256) void ln2_k(const float* __restrict__ resid,
                                             const float* __restrict__ d0,
                                             const float* __restrict__ d1,
                                             const float* __restrict__ biasN,
                                             const float* __restrict__ gamma,
                                             const float* __restrict__ beta,
                                             float* __restrict__ outf,
                                             __hip_bfloat16* __restrict__ outb) {
    const int row = blockIdx.x, tid = threadIdx.x;
    const size_t base = (size_t)row * 1024;
    float x[4], s = 0.f, sq = 0.f;
#pragma unroll
    for (int i = 0; i < 4; ++i) {
        const int c = tid + 256 * i;
        x[i] = resid[base + c] + d0[base + c] + d1[base + c] + biasN[c];
        s += x[i];
        sq += x[i] * x[i];
    }
#pragma unroll
    for (int off = 32; off > 0; off >>= 1) {
        s += __shfl_down(s, off);
        sq += __shfl_down(sq, off);
    }
    __shared__ float red[8];
    if ((tid & 63) == 0) {
        red[tid >> 6] = s;
        red[4 + (tid >> 6)] = sq;
    }
    __syncthreads();
    const float S = red[0] + red[1] + red[2] + red[3];
    const float Q2 = red[4] + red[5] + red[6] + red[7];
    const float mean = S * (1.f / 1024.f);
    const float var = Q2 * (1.f / 1024.f) - mean * mean;
    const float rstd = rsqrtf(var + 1e-5f);
#pragma unroll
    for (int i = 0; i < 4; ++i) {
        const int c = tid + 256 * i;
        const float y = (x[i] - mean) * rstd * gamma[c] + beta[c];
        outf[base + c] = y;
        if (outb) outb[base + c] = __float2bfloat16(y);
    }
}

// final LayerNorm: delta = d0+d1+d2+d3 + biasN, f32 output only.
__global__ __launch_bounds__(256) void ln4_k(const float* __restrict__ resid,
                                             const float* __restrict__ d0,
                                             const float* __restrict__ d1,
                                             const float* __restrict__ d2,
                                             const float* __restrict__ d3,
                                             const float* __restrict__ biasN,
                                             const float* __restrict__ gamma,
                                             const float* __restrict__ beta,
                                             float* __restrict__ outf) {
    const int row = blockIdx.x, tid = threadIdx.x;
    const size_t base = (size_t)row * 1024;
    float x[4], s = 0.f, sq = 0.f;
#pragma unroll
    for (int i = 0; i < 4; ++i) {
        const int c = tid + 256 * i;
        x[i] = resid[base + c] + d0[base + c] + d1[base + c] + d2[base + c] +
               d3[base + c] + biasN[c];
        s += x[i];
        sq += x[i] * x[i];
    }
#pragma unroll
    for (int off = 32; off > 0; off >>= 1) {
        s += __shfl_down(s, off);
        sq += __shfl_down(sq, off);
    }
    __shared__ float red[8];
    if ((tid & 63) == 0) {
        red[tid >> 6] = s;
        red[4 + (tid >> 6)] = sq;
    }
    __syncthreads();
    const float S = red[0] + red[1] + red[2] + red[3];
    const float Q2 = red[4] + red[5] + red[6] + red[7];
    const float mean = S * (1.f / 1024.f);
    const float var = Q2 * (1.f / 1024.f) - mean * mean;
    const float rstd = rsqrtf(var + 1e-5f);
#pragma unroll
    for (int i = 0; i < 4; ++i) {
        const int c = tid + 256 * i;
        outf[base + c] = (x[i] - mean) * rstd * gamma[c] + beta[c];
    }
}

// ---------------------------------------------------------------------------
extern "C" void kernel_launch(void* const* d_in, const int* in_sizes, int n_in,
                              void* d_out, int out_size, void* d_ws, size_t ws_size,
                              hipStream_t stream) {
    (void)in_sizes; (void)n_in; (void)out_size; (void)ws_size;
    const float* dec  = (const float*)d_in[0];
    const float* enc  = (const float*)d_in[1];
    const float* Wq_s = (const float*)d_in[2];
    const float* bq_s = (const float*)d_in[3];
    const float* Wk_s = (const float*)d_in[4];
    const float* bk_s = (const float*)d_in[5];
    const float* Wv_s = (const float*)d_in[6];
    const float* bv_s = (const float*)d_in[7];
    const float* Wo_s = (const float*)d_in[8];
    const float* bo_s = (const float*)d_in[9];
    const float* Wq_c = (const float*)d_in[10];
    const float* bq_c = (const float*)d_in[11];
    const float* Wk_c = (const float*)d_in[12];
    const float* bk_c = (const float*)d_in[13];
    const float* Wv_c = (const float*)d_in[14];
    const float* bv_c = (const float*)d_in[15];
    const float* Wo_c = (const float*)d_in[16];
    const float* bo_c = (const float*)d_in[17];
    const float* W1   = (const float*)d_in[18];
    const float* b1   = (const float*)d_in[19];
    const float* W2   = (const float*)d_in[20];
    const float* b2   = (const float*)d_in[21];
    const float* g1   = (const float*)d_in[22];
    const float* be1  = (const float*)d_in[23];
    const float* g2   = (const float*)d_in[24];
    const float* be2  = (const float*)d_in[25];
    const float* g3   = (const float*)d_in[26];
    const float* be3  = (const float*)d_in[27];

    char* w = (char*)d_ws;
    const size_t MB = 1ull << 20;
    __hip_bfloat16* Xdec   = (__hip_bfloat16*)(w + 0 * MB);    // 8 MB (dead after QKV)
    __hip_bfloat16* Xenc   = (__hip_bfloat16*)(w + 8 * MB);    // 8 MB (dead after pair)
    __hip_bfloat16* WtQKVs = (__hip_bfloat16*)(w + 16 * MB);   // 6 MB  [3072][1024]
    __hip_bfloat16* WtOs   = (__hip_bfloat16*)(w + 22 * MB);   // 2 MB
    __hip_bfloat16* WtQc   = (__hip_bfloat16*)(w + 24 * MB);   // 2 MB
    __hip_bfloat16* WtKVc  = (__hip_bfloat16*)(w + 26 * MB);   // 4 MB  [2048][1024]
    __hip_bfloat16* WtOc   = (__hip_bfloat16*)(w + 30 * MB);   // 2 MB
    __hip_bfloat16* Wt1    = (__hip_bfloat16*)(w + 32 * MB);   // 8 MB  [4096][1024]
    __hip_bfloat16* Wt2    = (__hip_bfloat16*)(w + 40 * MB);   // 8 MB  [1024][4096]
    float*          BiasQKVs = (float*)(w + 48 * MB);          // 12 KB
    float*          BiasKVc  = (float*)(w + 48 * MB + 65536);  // 8 KB
    __hip_bfloat16* QKV    = (__hip_bfloat16*)(w + 49 * MB);   // 24 MB
    __hip_bfloat16* Qc     = QKV;                               // 8 MB [4096][1024]
    __hip_bfloat16* KVc    = (__hip_bfloat16*)(w + 57 * MB);   // 16 MB [4096][2048]
    float*          Psplit = (float*)(w + 49 * MB);            // 32 MB [2][4096][1024]
    __hip_bfloat16* VtBuf  = (__hip_bfloat16*)(w + 73 * MB);   // 8 MB [2048][2048]
    __hip_bfloat16* Attn   = (__hip_bfloat16*)(w + 81 * MB);   // 8 MB
    float*          X1f    = (float*)(w + 97 * MB);            // 16 MB (dead after cross-LN)
    __hip_bfloat16* X1b    = (__hip_bfloat16*)(w + 113 * MB);  // 8 MB
    float*          X2f    = (float*)(w + 121 * MB);           // 16 MB
    __hip_bfloat16* X2b    = (__hip_bfloat16*)(w + 137 * MB);  // 8 MB
    __hip_bfloat16* H1     = (__hip_bfloat16*)(w + 145 * MB);  // 32 MB (FFN; scratch below)
    float*          FaO    = (float*)(w + 145 * MB);           // 16 MB self-flash partial O
    float*          FaL    = (float*)(w + 161 * MB);           // 256 KB self-flash partial l
    float*          FaOc   = (float*)(w + 145 * MB);           // 32 MB cross-flash partial O (dead before FFN)
    float*          FaLc   = (float*)(w + 48 * MB + 262144);   // 512 KB cross-flash partial l (bias region dead by then)
    float*          P0     = Psplit;
    float*          P1     = Psplit + (size_t)MROWS * 1024;
    float*          P2     = (float*)(w + 0 * MB);             // reuses dead Xdec/Xenc (16 MB)
    float*          P3     = X1f;                              // reuses dead X1f (16 MB)
    const int NOVT = 1 << 30;

    // ---- prep (2 launches) ----
    cast2_k<<<8192, 256, 0, stream>>>(dec, enc, Xdec, Xenc);
    prep_w_k<<<16404, 256, 0, stream>>>(Wq_s, Wk_s, Wv_s, Wq_c, Wk_c, Wv_c, Wo_s, Wo_c,
                                        W1, W2, bq_s, bk_s, bv_s, bk_c, bv_c,
                                        WtQKVs, WtQc, WtKVc, WtOs, WtOc, Wt1, Wt2,
                                        BiasQKVs, BiasKVc);

    // ---- self attention ----
    g256_k<<<dim3(12, 16), 512, 0, stream>>>(Xdec, WtQKVs, BiasQKVs, QKV, 3072, 1024, 0,
                                             VtBuf, 2048);
    flash_attn<<<dim3(48, 32), 256, 0, stream>>>(QKV, 3072, 0, QKV, 3072, 1024, VtBuf, Attn, 1,
                                                 FaO, FaL);
    fa_combine_k<<<512, 256, 0, stream>>>(FaO, FaL, Attn, 4, 16);
    gemm_sk2_k<<<dim3(8, 32, 2), 256, 0, stream>>>(Attn, WtOs, Psplit, 1024, 1024);
    ln2_k<<<MROWS, 256, 0, stream>>>(dec, P0, P1, bo_s, g1, be1, X1f, X1b);

    // ---- cross attention ----
    g256_pair_k<<<dim3(12, 16), 512, 0, stream>>>(X1b, WtQc, bq_c, Qc, 1024, 1024,
                                                  Xenc, WtKVc, BiasKVc, KVc, 2048, 1024,
                                                  VtBuf, 1024, 4);
    flash_attn<<<dim3(64, 32), 256, 0, stream>>>(Qc, 1024, 0, KVc, 2048, 0, VtBuf, Attn, 0,
                                                 FaOc, FaLc);
    fa_combine_k<<<1024, 256, 0, stream>>>(FaOc, FaLc, Attn, 5, 0);
    gemm_sk2_k<<<dim3(8, 32, 2), 256, 0, stream>>>(Attn, WtOc, Psplit, 1024, 1024);
    ln2_k<<<MROWS, 256, 0, stream>>>(X1f, P0, P1, bo_c, g2, be2, X2f, X2b);

    // ---- FFN ----
    g256_k<<<dim3(16, 16), 512, 0, stream>>>(X2b, Wt1, b1, H1, 4096, 1024, 1,
                                             nullptr, NOVT);
    g256_sk4_k<<<dim3(4, 16, 4), 512, 0, stream>>>(H1, Wt2, P0, P1, P2, P3, 1024, 4096);
    ln4_k<<<MROWS, 256, 0, stream>>>(X2f, P0, P1, P2, P3, b2, g3, be3, (float*)d_out);
}

// Round 9
// 524.305 us; speedup vs baseline: 1.0020x; 1.0020x over previous
//
#include <hip/hip_runtime.h>
#include <hip/hip_bf16.h>

typedef __attribute__((ext_vector_type(8))) short short8;
typedef __attribute__((ext_vector_type(4))) short short4v;
typedef __attribute__((ext_vector_type(4))) float floatx4;

#define TDIM 2048
#define BDIM 2
#define MROWS (BDIM * TDIM)   // 4096

#define ASM_VMCNT0() __asm__ volatile("s_waitcnt vmcnt(0)" ::: "memory")
#define ASM_VMCNT2() __asm__ volatile("s_waitcnt vmcnt(2)" ::: "memory")
#define ASM_VMCNT4() __asm__ volatile("s_waitcnt vmcnt(4)" ::: "memory")
#define ASM_LGKM0()  __asm__ volatile("s_waitcnt lgkmcnt(0)" ::: "memory")
#define ASM_BARRIER() __asm__ volatile("s_barrier" ::: "memory")

// K=16 bf16 MFMA wrapper (device pass picks the real builtin).
__device__ __forceinline__ floatx4 mfma16(short4v a, short4v b, floatx4 c) {
#if defined(__HIP_DEVICE_COMPILE__)
#if __has_builtin(__builtin_amdgcn_mfma_f32_16x16x16bf16_1k)
    return __builtin_amdgcn_mfma_f32_16x16x16bf16_1k(a, b, c, 0, 0, 0);
#else
    short8 az = {a[0], a[1], a[2], a[3], 0, 0, 0, 0};
    short8 bz = {b[0], b[1], b[2], b[3], 0, 0, 0, 0};
    return __builtin_amdgcn_mfma_f32_16x16x32_bf16(az, bz, c, 0, 0, 0);
#endif
#else
    (void)a; (void)b;
    return c;
#endif
}

// async global->LDS, 16B per lane; LDS dest = wave-uniform base + lane*16
__device__ __forceinline__ void gload_lds16(const void* g, void* l) {
    __builtin_amdgcn_global_load_lds((const __attribute__((address_space(1))) void*)g,
                                     (__attribute__((address_space(3))) void*)l, 16, 0, 0);
}

__device__ __forceinline__ short bf16s(float x) {
    __hip_bfloat16 h = __float2bfloat16(x);
    return *(short*)&h;
}

// native 2^x through the COMPILER (hazard-safe), not inline asm
__device__ __forceinline__ float fexp2(float x) {
#if defined(__HIP_DEVICE_COMPILE__)
#if __has_builtin(__builtin_amdgcn_exp2f)
    return __builtin_amdgcn_exp2f(x);
#else
    return exp2f(x);
#endif
#else
    return x;
#endif
}

// ---------------------------------------------------------------------------
// fused dual cast fp32 -> bf16 (dec then enc), 4 elems/thread
__global__ __launch_bounds__(256) void cast2_k(const float* __restrict__ a,
                                               const float* __restrict__ b,
                                               __hip_bfloat16* __restrict__ oa,
                                               __hip_bfloat16* __restrict__ ob) {
    const int blk = blockIdx.x;
    const float* in = (blk < 4096) ? a : b;
    __hip_bfloat16* out = (blk < 4096) ? oa : ob;
    const size_t base = (size_t)(blk & 4095) * 1024 + threadIdx.x * 4;
    float4 v = *(const float4*)&in[base];
    out[base + 0] = __float2bfloat16(v.x);
    out[base + 1] = __float2bfloat16(v.y);
    out[base + 2] = __float2bfloat16(v.z);
    out[base + 3] = __float2bfloat16(v.w);
}

// 32x32 transpose-cast tile helper
__device__ __forceinline__ void t32(float (*tile)[33], const float* __restrict__ in,
                                    __hip_bfloat16* __restrict__ out, int R, int C,
                                    int c0, int r0) {
    const int tx = threadIdx.x & 31, ty = threadIdx.x >> 5;
#pragma unroll
    for (int i = 0; i < 4; ++i)
        tile[ty + 8 * i][tx] = in[(size_t)(r0 + ty + 8 * i) * C + c0 + tx];
    __syncthreads();
#pragma unroll
    for (int i = 0; i < 4; ++i)
        out[(size_t)(c0 + ty + 8 * i) * R + r0 + tx] = __float2bfloat16(tile[tx][ty + 8 * i]);
}

// One fused kernel for ALL weight prep: 10 transposes + 2 bias concats.
__global__ __launch_bounds__(256) void prep_w_k(
    const float* __restrict__ Wq_s, const float* __restrict__ Wk_s, const float* __restrict__ Wv_s,
    const float* __restrict__ Wq_c, const float* __restrict__ Wk_c, const float* __restrict__ Wv_c,
    const float* __restrict__ Wo_s, const float* __restrict__ Wo_c,
    const float* __restrict__ W1, const float* __restrict__ W2,
    const float* __restrict__ bq_s, const float* __restrict__ bk_s, const float* __restrict__ bv_s,
    const float* __restrict__ bk_c, const float* __restrict__ bv_c,
    __hip_bfloat16* __restrict__ WtQKVs, __hip_bfloat16* __restrict__ WtQc,
    __hip_bfloat16* __restrict__ WtKVc, __hip_bfloat16* __restrict__ WtOs,
    __hip_bfloat16* __restrict__ WtOc, __hip_bfloat16* __restrict__ Wt1,
    __hip_bfloat16* __restrict__ Wt2,
    float* __restrict__ BiasQKVs, float* __restrict__ BiasKVc) {
    __shared__ float tile[32][33];
    const int t = blockIdx.x;
    if (t < 6144) {  // per-head stacks: R=1024, C=64, 16 slabs, 64 tiles/slab
        const int seg = t >> 10, tl = t & 1023;
        const float* s;
        __hip_bfloat16* d;
        if (seg == 0) { s = Wq_s; d = WtQKVs; }
        else if (seg == 1) { s = Wk_s; d = WtQKVs + 1048576; }
        else if (seg == 2) { s = Wv_s; d = WtQKVs + 2097152; }
        else if (seg == 3) { s = Wq_c; d = WtQc; }
        else if (seg == 4) { s = Wk_c; d = WtKVc; }
        else { s = Wv_c; d = WtKVc + 1048576; }
        const int slab = tl >> 6, rem = tl & 63;
        t32(tile, s + (size_t)slab * 65536, d + (size_t)slab * 65536, 1024, 64,
            (rem & 1) * 32, (rem >> 1) * 32);
    } else if (t < 8192) {  // Wo_s / Wo_c: 1024x1024
        const int rem = (t - 6144) & 1023;
        const float* s = (t < 7168) ? Wo_s : Wo_c;
        __hip_bfloat16* d = (t < 7168) ? WtOs : WtOc;
        t32(tile, s, d, 1024, 1024, (rem & 31) * 32, (rem >> 5) * 32);
    } else if (t < 12288) {  // W1: R=1024 C=4096
        const int rem = t - 8192;
        t32(tile, W1, Wt1, 1024, 4096, (rem & 127) * 32, (rem >> 7) * 32);
    } else if (t < 16384) {  // W2: R=4096 C=1024
        const int rem = t - 12288;
        t32(tile, W2, Wt2, 4096, 1024, (rem & 31) * 32, (rem >> 5) * 32);
    } else if (t < 16396) {  // concat3 -> BiasQKVs
        const int i = (t - 16384) * 256 + threadIdx.x;
        BiasQKVs[i] = (i < 1024) ? bq_s[i] : (i < 2048 ? bk_s[i - 1024] : bv_s[i - 2048]);
    } else {  // concat2 -> BiasKVc
        const int i = (t - 16396) * 256 + threadIdx.x;
        BiasKVc[i] = (i < 1024) ? bk_c[i] : bv_c[i - 1024];
    }
}

// ---------------------------------------------------------------------------
// 128x128 4-wave GEMM core (proven 3 WG/CU path; used for QKV, pair, Wo GEMMs).
__device__ __forceinline__ void gemm_core(
    const __hip_bfloat16* __restrict__ A, const __hip_bfloat16* __restrict__ Bt,
    int K, int kBeg, int kLen,
    const float* __restrict__ bias, __hip_bfloat16* __restrict__ C, int ldc,
    float* __restrict__ Pf,
    __hip_bfloat16* __restrict__ Vt, int vt_col0, int relu,
    int m0, int n0, __hip_bfloat16* sm) {
    const int tid = threadIdx.x;
    const int lane = tid & 63, wave = tid >> 6;
    const int quad = lane >> 4, l16 = lane & 15;
    const int wm = (wave >> 1) * 64, wn = (wave & 1) * 64;
    const int lrow = lane >> 3;
    const int gsw = (((lane & 7) ^ lrow)) * 8;  // swizzled source column (elems)
    const int sw7 = l16 & 7;                    // reader swizzle key (row&7)
    const __hip_bfloat16* gA = A + (size_t)(m0 + wave * 32 + lrow) * K + kBeg + gsw;
    const __hip_bfloat16* gB = Bt + (size_t)(n0 + wave * 32 + lrow) * K + kBeg + gsw;
    __hip_bfloat16* lA = sm + wave * 2048;
    __hip_bfloat16* lB = sm + 16384 + wave * 2048;
    floatx4 acc[4][4] = {};
    const int T = kLen >> 6;
#pragma unroll
    for (int i = 0; i < 4; ++i) {
        gload_lds16(gA + (size_t)i * 8 * K, lA + i * 512);
        gload_lds16(gB + (size_t)i * 8 * K, lB + i * 512);
    }
    for (int t = 0; t < T; ++t) {
        ASM_VMCNT0();
        ASM_BARRIER();
        if (t + 1 < T) {
            const int koff = (t + 1) << 6;
            const int b = ((t + 1) & 1) * 8192;
#pragma unroll
            for (int i = 0; i < 4; ++i) {
                gload_lds16(gA + (size_t)i * 8 * K + koff, lA + b + i * 512);
                gload_lds16(gB + (size_t)i * 8 * K + koff, lB + b + i * 512);
            }
        }
        const __hip_bfloat16* cA = sm + (t & 1) * 8192;
        const __hip_bfloat16* cB = sm + 16384 + (t & 1) * 8192;
#pragma unroll
        for (int kc = 0; kc < 2; ++kc) {
            short8 af[4], bfr[4];
#pragma unroll
            for (int i = 0; i < 4; ++i) {
                af[i] = *(const short8*)&cA[(wm + i * 16 + l16) * 64 +
                                            (((kc * 4 + quad) ^ sw7) * 8)];
                bfr[i] = *(const short8*)&cB[(wn + i * 16 + l16) * 64 +
                                             (((kc * 4 + quad) ^ sw7) * 8)];
            }
#pragma unroll
            for (int mi = 0; mi < 4; ++mi)
#pragma unroll
                for (int ni = 0; ni < 4; ++ni)
                    acc[mi][ni] =
                        __builtin_amdgcn_mfma_f32_16x16x32_bf16(af[mi], bfr[ni], acc[mi][ni], 0, 0, 0);
        }
    }
    // epilogue
    if (Pf) {
#pragma unroll
        for (int ni = 0; ni < 4; ++ni) {
            const int col = n0 + wn + ni * 16 + l16;
#pragma unroll
            for (int mi = 0; mi < 4; ++mi)
#pragma unroll
                for (int r = 0; r < 4; ++r) {
                    const int row = m0 + wm + mi * 16 + quad * 4 + r;
                    Pf[(size_t)row * ldc + col] = acc[mi][ni][r];
                }
        }
    } else {
        const bool toVt = (n0 >= vt_col0);
#pragma unroll
        for (int ni = 0; ni < 4; ++ni) {
            const int col = n0 + wn + ni * 16 + l16;
            const float bv = bias[col];
#pragma unroll
            for (int mi = 0; mi < 4; ++mi) {
                const int row0 = m0 + wm + mi * 16 + quad * 4;
                if (toVt) {
                    const int b = row0 >> 11, t0 = row0 & (TDIM - 1);
                    short4v pk;
#pragma unroll
                    for (int r = 0; r < 4; ++r) pk[r] = bf16s(acc[mi][ni][r] + bv);
                    *(short4v*)&Vt[((size_t)(b * 1024 + (col - vt_col0)) << 11) + t0] = pk;
                } else {
#pragma unroll
                    for (int r = 0; r < 4; ++r) {
                        float v = acc[mi][ni][r] + bv;
                        if (relu) v = fmaxf(v, 0.f);
                        C[(size_t)(row0 + r) * ldc + col] = __float2bfloat16(v);
                    }
                }
            }
        }
    }
}

__global__ __launch_bounds__(256) void gemm_bf16_k(const __hip_bfloat16* __restrict__ A,
                                                   const __hip_bfloat16* __restrict__ Bt,
                                                   const float* __restrict__ bias,
                                                   __hip_bfloat16* __restrict__ C,
                                                   int N, int K, int relu,
                                                   __hip_bfloat16* __restrict__ Vt, int vt_col0) {
    __shared__ __hip_bfloat16 sm[2 * 128 * 64 * 2];
    gemm_core(A, Bt, K, 0, K, bias, C, N, nullptr, Vt, vt_col0, relu,
              blockIdx.y * 128, blockIdx.x * 128, sm);
}

__global__ __launch_bounds__(256) void gemm_sk2_k(const __hip_bfloat16* __restrict__ A,
                                                  const __hip_bfloat16* __restrict__ Bt,
                                                  float* __restrict__ Pf, int N, int K) {
    __shared__ __hip_bfloat16 sm[2 * 128 * 64 * 2];
    const int z = blockIdx.z;
    gemm_core(A, Bt, K, z * (K >> 1), K >> 1, nullptr, nullptr, N,
              Pf + (size_t)z * MROWS * N, nullptr, 1 << 30, 0,
              blockIdx.y * 128, blockIdx.x * 128, sm);
}

__global__ __launch_bounds__(256) void gemm_pair_k(
    const __hip_bfloat16* __restrict__ A1, const __hip_bfloat16* __restrict__ Bt1,
    const float* __restrict__ bias1, __hip_bfloat16* __restrict__ C1, int N1, int K1,
    const __hip_bfloat16* __restrict__ A2, const __hip_bfloat16* __restrict__ Bt2,
    const float* __restrict__ bias2, __hip_bfloat16* __restrict__ C2, int N2, int K2,
    __hip_bfloat16* __restrict__ Vt2, int vtc2, int nx1) {
    __shared__ __hip_bfloat16 sm[2 * 128 * 64 * 2];
    if ((int)blockIdx.x < nx1)
        gemm_core(A1, Bt1, K1, 0, K1, bias1, C1, N1, nullptr, nullptr, 1 << 30, 0,
                  blockIdx.y * 128, blockIdx.x * 128, sm);
    else
        gemm_core(A2, Bt2, K2, 0, K2, bias2, C2, N2, nullptr, Vt2, vtc2, 0,
                  blockIdx.y * 128, (blockIdx.x - nx1) * 128, sm);
}

// ---------------------------------------------------------------------------
// 256x256 8-wave GEMM core, deep-prefetch double-buffer (kept for the two
// exact-fill FFN GEMMs: 256 blocks = 1/CU machine-wide).
__device__ __forceinline__ void gemm256_core(
    const __hip_bfloat16* __restrict__ A, const __hip_bfloat16* __restrict__ Bt,
    int K, int kBeg, int kLen,
    const float* __restrict__ bias, __hip_bfloat16* __restrict__ C, int ldc,
    float* __restrict__ Pf,
    __hip_bfloat16* __restrict__ Vt, int vt_col0, int relu,
    int m0, int n0, __hip_bfloat16* sm) {
    const int tid = threadIdx.x;
    const int lane = tid & 63, wave = tid >> 6;
    const int quad = lane >> 4, l16 = lane & 15;
    const int wm = (wave >> 2) * 128, wn = (wave & 3) * 64;
    const int lrow = lane >> 3;
    const int gsw = ((lane & 7) ^ lrow) * 8;
    const int sw7 = l16 & 7;
    const __hip_bfloat16* aSrc = A + (size_t)(m0 + wave * 16 + lrow) * K + kBeg + gsw;
    const __hip_bfloat16* bSrc = Bt + (size_t)(n0 + wave * 16 + lrow) * K + kBeg + gsw;
    floatx4 acc[8][4] = {};
    const int T = kLen >> 6;
    // prologue: stage K-step 0 into buf0 (8 DMAs/wave)
#pragma unroll
    for (int h = 0; h < 2; ++h)
#pragma unroll
        for (int j = 0; j < 2; ++j) {
            const size_t ro = (size_t)(h * 128 + j * 8);
            gload_lds16(aSrc + ro * K, sm + (h * 128 + wave * 16 + j * 8) * 64);
            gload_lds16(bSrc + ro * K, sm + 16384 + (h * 128 + wave * 16 + j * 8) * 64);
        }
    for (int t = 0; t < T; ++t) {
        const int c = t & 1;
        const __hip_bfloat16* cA = sm + c * 32768;
        const __hip_bfloat16* cB = cA + 16384;
        ASM_VMCNT0();   // own step-t DMAs complete (only outstanding vmem)
        ASM_BARRIER();  // ALL waves' step-t DMAs complete
        if (t + 1 < T) {  // issue all 8 next-step DMAs NOW (full-step distance)
            __hip_bfloat16* dst = sm + (1 - c) * 32768;
            const size_t nko = (size_t)(t + 1) * 64;
#pragma unroll
            for (int h = 0; h < 2; ++h)
#pragma unroll
                for (int j = 0; j < 2; ++j) {
                    const size_t ro = (size_t)(h * 128 + j * 8);
                    gload_lds16(aSrc + ro * K + nko, dst + (h * 128 + wave * 16 + j * 8) * 64);
                    gload_lds16(bSrc + ro * K + nko, dst + 16384 + (h * 128 + wave * 16 + j * 8) * 64);
                }
        }
#pragma unroll
        for (int kh = 0; kh < 2; ++kh) {
            const int gk = ((kh * 4 + quad) ^ sw7) * 8;
            short8 af[4], bfr[4];
#pragma unroll
            for (int i = 0; i < 4; ++i) {
                af[i] = *(const short8*)&cA[(wm + i * 16 + l16) * 64 + gk];
                bfr[i] = *(const short8*)&cB[(wn + i * 16 + l16) * 64 + gk];
            }
            __builtin_amdgcn_s_setprio(1);
#pragma unroll
            for (int mi = 0; mi < 4; ++mi)
#pragma unroll
                for (int ni = 0; ni < 4; ++ni)
                    acc[mi][ni] = __builtin_amdgcn_mfma_f32_16x16x32_bf16(af[mi], bfr[ni], acc[mi][ni], 0, 0, 0);
            __builtin_amdgcn_s_setprio(0);
#pragma unroll
            for (int i = 0; i < 4; ++i)
                af[i] = *(const short8*)&cA[(wm + 64 + i * 16 + l16) * 64 + gk];
            __builtin_amdgcn_s_setprio(1);
#pragma unroll
            for (int mi = 0; mi < 4; ++mi)
#pragma unroll
                for (int ni = 0; ni < 4; ++ni)
                    acc[4 + mi][ni] = __builtin_amdgcn_mfma_f32_16x16x32_bf16(af[mi], bfr[ni], acc[4 + mi][ni], 0, 0, 0);
            __builtin_amdgcn_s_setprio(0);
        }
    }
    // epilogue (same formulas as gemm_core, mi now 0..7)
    if (Pf) {
#pragma unroll
        for (int ni = 0; ni < 4; ++ni) {
            const int col = n0 + wn + ni * 16 + l16;
#pragma unroll
            for (int mi = 0; mi < 8; ++mi)
#pragma unroll
                for (int r = 0; r < 4; ++r) {
                    const int row = m0 + wm + mi * 16 + quad * 4 + r;
                    Pf[(size_t)row * ldc + col] = acc[mi][ni][r];
                }
        }
    } else {
        const bool toVt = (n0 >= vt_col0);
#pragma unroll
        for (int ni = 0; ni < 4; ++ni) {
            const int col = n0 + wn + ni * 16 + l16;
            const float bv = bias[col];
#pragma unroll
            for (int mi = 0; mi < 8; ++mi) {
                const int row0 = m0 + wm + mi * 16 + quad * 4;
                if (toVt) {
                    const int b = row0 >> 11, t0 = row0 & (TDIM - 1);
                    short4v pk;
#pragma unroll
                    for (int r = 0; r < 4; ++r) pk[r] = bf16s(acc[mi][ni][r] + bv);
                    *(short4v*)&Vt[((size_t)(b * 1024 + (col - vt_col0)) << 11) + t0] = pk;
                } else {
#pragma unroll
                    for (int r = 0; r < 4; ++r) {
                        float v = acc[mi][ni][r] + bv;
                        if (relu) v = fmaxf(v, 0.f);
                        C[(size_t)(row0 + r) * ldc + col] = __float2bfloat16(v);
                    }
                }
            }
        }
    }
}

__global__ __launch_bounds__(512, 2) void g256_k(const __hip_bfloat16* __restrict__ A,
                                                 const __hip_bfloat16* __restrict__ Bt,
                                                 const float* __restrict__ bias,
                                                 __hip_bfloat16* __restrict__ C,
                                                 int N, int K, int relu,
                                                 __hip_bfloat16* __restrict__ Vt, int vt_col0) {
    __shared__ __hip_bfloat16 sm[65536];  // 128 KiB
    gemm256_core(A, Bt, K, 0, K, bias, C, N, nullptr, Vt, vt_col0, relu,
                 blockIdx.y * 256, blockIdx.x * 256, sm);
}

// FFN2 split-K 4: 4 f32 partial outputs (combined by ln4_k). 256 blocks.
__global__ __launch_bounds__(512, 2) void g256_sk4_k(const __hip_bfloat16* __restrict__ A,
                                                     const __hip_bfloat16* __restrict__ Bt,
                                                     float* __restrict__ Pf0, float* __restrict__ Pf1,
                                                     float* __restrict__ Pf2, float* __restrict__ Pf3,
                                                     int N, int K) {
    __shared__ __hip_bfloat16 sm[65536];
    const int z = blockIdx.z;
    float* pf = (z == 0) ? Pf0 : (z == 1) ? Pf1 : (z == 2) ? Pf2 : Pf3;
    gemm256_core(A, Bt, K, z * (K >> 2), K >> 2, nullptr, nullptr, N, pf,
                 nullptr, 1 << 30, 0, blockIdx.y * 256, blockIdx.x * 256, sm);
}

// ---------------------------------------------------------------------------
// Flash attention, register-resident P. Processes k-tiles [tBeg, tEnd).
// k-loop unrolled x2 so the LDS double-buffer offset (CB/NB) is a literal
// (ds_read offset-immediate folding). Split K/V waits: per wave DMAs are
// issued K,K,V,V; tile top waits vmcnt(2) (K ready, V in flight), QK^T+exp
// overlap V arrival; vmcnt(4) before PV (V ready, next tile's 4 prefetch
// DMAs stay in flight). Invariant: exactly 4 DMAs outstanding at tile top
// (last tile re-stages itself to keep counts uniform).
__device__ __forceinline__ void flash_one(
    const __hip_bfloat16* __restrict__ Q, int ldq, int qc0,
    const __hip_bfloat16* __restrict__ Kp, int ldk,
    const __hip_bfloat16* __restrict__ Vp,
    __hip_bfloat16* __restrict__ O, int causal, int q0, size_t rowb, int h,
    int tBeg, int tEnd, float* __restrict__ Opart, float* __restrict__ lpart,
    __hip_bfloat16* sK, __hip_bfloat16* sV) {
    const int tid = threadIdx.x, lane = tid & 63, wave = tid >> 6;
    const int quad = lane >> 4, l16 = lane & 15;
    const int lrow = lane >> 3;
    const int gsw = ((lane & 7) ^ lrow) * 8;  // DMA swizzled source col (elems)
    const int sw7 = l16 & 7;
    short8 qf[2];
    {
        const __hip_bfloat16* qp = Q + (rowb + q0 + wave * 16 + l16) * (size_t)ldq + qc0 + h * 64;
        const float qs = 0.18033688f;  // 0.125 * log2(e)
        short8 r0 = *(const short8*)(qp + quad * 8);
        short8 r1 = *(const short8*)(qp + 32 + quad * 8);
#pragma unroll
        for (int j = 0; j < 8; ++j) {
            qf[0][j] = bf16s(__uint_as_float(((unsigned)(unsigned short)r0[j]) << 16) * qs);
            qf[1][j] = bf16s(__uint_as_float(((unsigned)(unsigned short)r1[j]) << 16) * qs);
        }
    }
    short4v ones4;
#pragma unroll
    for (int j = 0; j < 4; ++j) ones4[j] = (short)0x3F80;  // bf16 1.0
    floatx4 Ot[4] = {};  // Ot[dt][r] = O[q=..+l16][d=dt*16+quad*4+r]
    floatx4 accl = {};
    const int nDiag = q0 >> 6;
    const int rb = wave * 16;
    ASM_LGKM0();
    ASM_BARRIER();
    {   // prologue stage: K,K then V,V (order matters for counted waits)
        const int s0 = tBeg << 6, pb = (tBeg & 1) * 4096;
        gload_lds16(&Kp[(rowb + s0 + rb + lrow) * (size_t)ldk + gsw], &sK[pb + rb * 64]);
        gload_lds16(&Kp[(rowb + s0 + rb + 8 + lrow) * (size_t)ldk + gsw], &sK[pb + (rb + 8) * 64]);
        gload_lds16(&Vp[(size_t)(rb + lrow) * TDIM + s0 + gsw], &sV[pb + rb * 64]);
        gload_lds16(&Vp[(size_t)(rb + 8 + lrow) * TDIM + s0 + gsw], &sV[pb + (rb + 8) * 64]);
    }

#define FA_TILE(TT, CB, NB)                                                              \
    do {                                                                                 \
        const int tt = (TT);                                                             \
        ASM_VMCNT2();  /* this tile's K landed (V may still be in flight) */             \
        ASM_BARRIER();                                                                   \
        {   /* prefetch next tile (clamped on last -> uniform wait counts) */            \
            const int nx = (tt + 1 < tEnd) ? tt + 1 : tt;                                \
            const int s1 = nx << 6;                                                      \
            gload_lds16(&Kp[(rowb + s1 + rb + lrow) * (size_t)ldk + gsw],                \
                        &sK[(NB) + rb * 64]);                                            \
            gload_lds16(&Kp[(rowb + s1 + rb + 8 + lrow) * (size_t)ldk + gsw],            \
                        &sK[(NB) + (rb + 8) * 64]);                                      \
            gload_lds16(&Vp[(size_t)(rb + lrow) * TDIM + s1 + gsw],                      \
                        &sV[(NB) + rb * 64]);                                            \
            gload_lds16(&Vp[(size_t)(rb + 8 + lrow) * TDIM + s1 + gsw],                  \
                        &sV[(NB) + (rb + 8) * 64]);                                      \
        }                                                                                \
        floatx4 Sf[4] = {};                                                              \
        _Pragma("unroll") for (int st = 0; st < 4; ++st) {                               \
            short8 b0 = *(const short8*)&sK[(CB) + (st * 16 + l16) * 64 +                \
                                            ((quad ^ sw7) * 8)];                         \
            short8 b1 = *(const short8*)&sK[(CB) + (st * 16 + l16) * 64 +                \
                                            (((4 + quad) ^ sw7) * 8)];                   \
            Sf[st] = __builtin_amdgcn_mfma_f32_16x16x32_bf16(b0, qf[0], Sf[st], 0, 0, 0);\
            Sf[st] = __builtin_amdgcn_mfma_f32_16x16x32_bf16(b1, qf[1], Sf[st], 0, 0, 0);\
        }                                                                                \
        _Pragma("unroll") for (int st = 0; st < 4; ++st)                                 \
            _Pragma("unroll") for (int r = 0; r < 4; ++r) Sf[st][r] = fexp2(Sf[st][r]);  \
        if (causal && tt == nDiag) {                                                     \
            const int qr = wave * 16 + l16;                                              \
            _Pragma("unroll") for (int st = 0; st < 4; ++st)                             \
                _Pragma("unroll") for (int r = 0; r < 4; ++r)                            \
                    if (st * 16 + quad * 4 + r > qr) Sf[st][r] = 0.f;                    \
        }                                                                                \
        short4v pf[4];                                                                   \
        _Pragma("unroll") for (int st = 0; st < 4; ++st)                                 \
            _Pragma("unroll") for (int r = 0; r < 4; ++r) pf[st][r] = bf16s(Sf[st][r]);  \
        ASM_VMCNT4();  /* this tile's V landed (next tile's 4 DMAs in flight) */         \
        ASM_BARRIER();                                                                   \
        _Pragma("unroll") for (int st = 0; st < 4; ++st) accl = mfma16(ones4, pf[st], accl); \
        _Pragma("unroll") for (int dt = 0; dt < 4; ++dt)                                 \
            _Pragma("unroll") for (int st = 0; st < 4; ++st) {                           \
                short4v av = *(const short4v*)&sV[(CB) + (dt * 16 + l16) * 64 +          \
                                                 (((st * 2 + (quad >> 1)) ^ sw7) * 8) +  \
                                                 (quad & 1) * 4];                        \
                Ot[dt] = mfma16(av, pf[st], Ot[dt]);                                     \
            }                                                                            \
    } while (0)

    int t = tBeg;
    if (t & 1) { FA_TILE(t, 4096, 0); ++t; }
    for (; t + 1 < tEnd; t += 2) {
        FA_TILE(t, 0, 4096);
        FA_TILE(t + 1, 4096, 0);
    }
    if (t < tEnd) FA_TILE(t, 0, 4096);
#undef FA_TILE

    if (Opart) {
        const int qrow = wave * 16 + l16;
#pragma unroll
        for (int dt = 0; dt < 4; ++dt)
            *(floatx4*)&Opart[qrow * 64 + dt * 16 + quad * 4] = Ot[dt];
        if (quad == 0) lpart[qrow] = accl[0];
    } else {
        const float inv = 1.0f / accl[0];
        __hip_bfloat16* op = O + (rowb + q0 + wave * 16 + l16) * (size_t)1024 + h * 64 + quad * 4;
#pragma unroll
        for (int dt = 0; dt < 4; ++dt) {
            short4v pk;
#pragma unroll
            for (int r = 0; r < 4; ++r) pk[r] = bf16s(Ot[dt][r] * inv);
            *(short4v*)(op + dt * 16) = pk;
        }
    }
}

// XCD-aware remap (T1): all q-blocks of one (b,h) land on one XCD so its
// K/V head is fetched into that XCD's L2 exactly once. Linear wgid w:
// bh = (w&7)*4 + ((w>>3)&3), bx = w>>5. Bijective for gy=32, gx in {32,48}.
// causal=1: grid (48,32):
//   bx 0..31  -> q-tiles i=16+(bx>>1) split into half k-ranges hh=bx&1 (partials)
//   bx 32..47 -> q-tiles i=47-bx unsplit (direct output)
// causal=0: grid (32,32), one full q-tile per block (no split -- R8 showed
// the cross k-split regresses: occupancy dropped, no latency win).
__global__ __launch_bounds__(256) void flash_attn(const __hip_bfloat16* __restrict__ Q, int ldq, int qc0,
                                                  const __hip_bfloat16* __restrict__ K, int ldk, int kc0,
                                                  const __hip_bfloat16* __restrict__ Vt,
                                                  __hip_bfloat16* __restrict__ O, int causal,
                                                  float* __restrict__ Opart,
                                                  float* __restrict__ lpart) {
    __shared__ __hip_bfloat16 sK[2 * 64 * 64];
    __shared__ __hip_bfloat16 sV[2 * 64 * 64];
    const int w = (int)blockIdx.y * (int)gridDim.x + (int)blockIdx.x;
    const int bh = (w & 7) * 4 + ((w >> 3) & 3);
    const int bx = w >> 5;
    const int b = bh >> 4, h = bh & 15;
    const size_t rowb = (size_t)b * TDIM;
    const __hip_bfloat16* Kp = K + kc0 + h * 64;
    const __hip_bfloat16* Vp = Vt + ((size_t)(b * 1024 + h * 64) << 11);
    if (causal) {
        if (bx < 32) {
            const int i = 16 + (bx >> 1), hh = bx & 1;
            const int n = i + 1, n2 = n >> 1;
            const int p = bh * 16 + (i - 16);
            float* Op = Opart + (size_t)p * 8192 + hh * 4096;
            float* lp = lpart + p * 128 + hh * 64;
            flash_one(Q, ldq, qc0, Kp, ldk, Vp, O, 1, i * 64, rowb, h,
                      hh ? n2 : 0, hh ? n : n2, Op, lp, sK, sV);
        } else {
            const int i = 47 - bx;
            flash_one(Q, ldq, qc0, Kp, ldk, Vp, O, 1, i * 64, rowb, h,
                      0, i + 1, nullptr, nullptr, sK, sV);
        }
    } else {
        flash_one(Q, ldq, qc0, Kp, ldk, Vp, O, 0, bx * 64, rowb, h,
                  0, TDIM >> 6, nullptr, nullptr, sK, sV);
    }
}

// combine split-k flash partials: O = (O0+O1)/(l0+l1). grid 512 blocks (causal).
__global__ __launch_bounds__(256) void fa_combine_k(const float* __restrict__ Opart,
                                                    const float* __restrict__ lpart,
                                                    __hip_bfloat16* __restrict__ O) {
    const int p = blockIdx.x;            // = bh*16 + (i-16)
    const int bh = p >> 4, i = (p & 15) + 16;
    const int b = bh >> 4, h = bh & 15;
    const int tid = threadIdx.x;
    const int q = tid >> 2, dseg = (tid & 3) * 16;
    const float* O0 = Opart + (size_t)p * 8192;
    const float* O1 = O0 + 4096;
    const float inv = 1.f / (lpart[p * 128 + q] + lpart[p * 128 + 64 + q]);
    __hip_bfloat16* op = O + ((size_t)(b * TDIM) + i * 64 + q) * 1024 + h * 64 + dseg;
#pragma unroll
    for (int j = 0; j < 4; ++j) {
        floatx4 a = *(const floatx4*)&O0[q * 64 + dseg + j * 4];
        floatx4 c = *(const floatx4*)&O1[q * 64 + dseg + j * 4];
        short4v pk;
#pragma unroll
        for (int r = 0; r < 4; ++r) pk[r] = bf16s((a[r] + c[r]) * inv);
        *(short4v*)(op + j * 4) = pk;
    }
}

// ---------------------------------------------------------------------------
// LayerNorm with fused split-K reduction: delta = d0 + d1 + biasN.
__global__ __launch_bounds__(256) void ln2_k(const float* __restrict__ resid,
                                             const float* __restrict__ d0,
                                             const float* __restrict__ d1,
                                             const float* __restrict__ biasN,
                                             const float* __restrict__ gamma,
                                             const float* __restrict__ beta,
                                             float* __restrict__ outf,
                                             __hip_bfloat16* __restrict__ outb) {
    const int row = blockIdx.x, tid = threadIdx.x;
    const size_t base = (size_t)row * 1024;
    float x[4], s = 0.f, sq = 0.f;
#pragma unroll
    for (int i = 0; i < 4; ++i) {
        const int c = tid + 256 * i;
        x[i] = resid[base + c] + d0[base + c] + d1[base + c] + biasN[c];
        s += x[i];
        sq += x[i] * x[i];
    }
#pragma unroll
    for (int off = 32; off > 0; off >>= 1) {
        s += __shfl_down(s, off);
        sq += __shfl_down(sq, off);
    }
    __shared__ float red[8];
    if ((tid & 63) == 0) {
        red[tid >> 6] = s;
        red[4 + (tid >> 6)] = sq;
    }
    __syncthreads();
    const float S = red[0] + red[1] + red[2] + red[3];
    const float Q2 = red[4] + red[5] + red[6] + red[7];
    const float mean = S * (1.f / 1024.f);
    const float var = Q2 * (1.f / 1024.f) - mean * mean;
    const float rstd = rsqrtf(var + 1e-5f);
#pragma unroll
    for (int i = 0; i < 4; ++i) {
        const int c = tid + 256 * i;
        const float y = (x[i] - mean) * rstd * gamma[c] + beta[c];
        outf[base + c] = y;
        if (outb) outb[base + c] = __float2bfloat16(y);
    }
}

// final LayerNorm: delta = d0+d1+d2+d3 + biasN, f32 output only.
__global__ __launch_bounds__(256) void ln4_k(const float* __restrict__ resid,
                                             const float* __restrict__ d0,
                                             const float* __restrict__ d1,
                                             const float* __restrict__ d2,
                                             const float* __restrict__ d3,
                                             const float* __restrict__ biasN,
                                             const float* __restrict__ gamma,
                                             const float* __restrict__ beta,
                                             float* __restrict__ outf) {
    const int row = blockIdx.x, tid = threadIdx.x;
    const size_t base = (size_t)row * 1024;
    float x[4], s = 0.f, sq = 0.f;
#pragma unroll
    for (int i = 0; i < 4; ++i) {
        const int c = tid + 256 * i;
        x[i] = resid[base + c] + d0[base + c] + d1[base + c] + d2[base + c] +
               d3[base + c] + biasN[c];
        s += x[i];
        sq += x[i] * x[i];
    }
#pragma unroll
    for (int off = 32; off > 0; off >>= 1) {
        s += __shfl_down(s, off);
        sq += __shfl_down(sq, off);
    }
    __shared__ float red[8];
    if ((tid & 63) == 0) {
        red[tid >> 6] = s;
        red[4 + (tid >> 6)] = sq;
    }
    __syncthreads();
    const float S = red[0] + red[1] + red[2] + red[3];
    const float Q2 = red[4] + red[5] + red[6] + red[7];
    const float mean = S * (1.f / 1024.f);
    const float var = Q2 * (1.f / 1024.f) - mean * mean;
    const float rstd = rsqrtf(var + 1e-5f);
#pragma unroll
    for (int i = 0; i < 4; ++i) {
        const int c = tid + 256 * i;
        outf[base + c] = (x[i] - mean) * rstd * gamma[c] + beta[c];
    }
}

// ---------------------------------------------------------------------------
extern "C" void kernel_launch(void* const* d_in, const int* in_sizes, int n_in,
                              void* d_out, int out_size, void* d_ws, size_t ws_size,
                              hipStream_t stream) {
    (void)in_sizes; (void)n_in; (void)out_size; (void)ws_size;
    const float* dec  = (const float*)d_in[0];
    const float* enc  = (const float*)d_in[1];
    const float* Wq_s = (const float*)d_in[2];
    const float* bq_s = (const float*)d_in[3];
    const float* Wk_s = (const float*)d_in[4];
    const float* bk_s = (const float*)d_in[5];
    const float* Wv_s = (const float*)d_in[6];
    const float* bv_s = (const float*)d_in[7];
    const float* Wo_s = (const float*)d_in[8];
    const float* bo_s = (const float*)d_in[9];
    const float* Wq_c = (const float*)d_in[10];
    const float* bq_c = (const float*)d_in[11];
    const float* Wk_c = (const float*)d_in[12];
    const float* bk_c = (const float*)d_in[13];
    const float* Wv_c = (const float*)d_in[14];
    const float* bv_c = (const float*)d_in[15];
    const float* Wo_c = (const float*)d_in[16];
    const float* bo_c = (const float*)d_in[17];
    const float* W1   = (const float*)d_in[18];
    const float* b1   = (const float*)d_in[19];
    const float* W2   = (const float*)d_in[20];
    const float* b2   = (const float*)d_in[21];
    const float* g1   = (const float*)d_in[22];
    const float* be1  = (const float*)d_in[23];
    const float* g2   = (const float*)d_in[24];
    const float* be2  = (const float*)d_in[25];
    const float* g3   = (const float*)d_in[26];
    const float* be3  = (const float*)d_in[27];

    char* w = (char*)d_ws;
    const size_t MB = 1ull << 20;
    __hip_bfloat16* Xdec   = (__hip_bfloat16*)(w + 0 * MB);    // 8 MB (dead after QKV)
    __hip_bfloat16* Xenc   = (__hip_bfloat16*)(w + 8 * MB);    // 8 MB (dead after pair)
    __hip_bfloat16* WtQKVs = (__hip_bfloat16*)(w + 16 * MB);   // 6 MB  [3072][1024]
    __hip_bfloat16* WtOs   = (__hip_bfloat16*)(w + 22 * MB);   // 2 MB
    __hip_bfloat16* WtQc   = (__hip_bfloat16*)(w + 24 * MB);   // 2 MB
    __hip_bfloat16* WtKVc  = (__hip_bfloat16*)(w + 26 * MB);   // 4 MB  [2048][1024]
    __hip_bfloat16* WtOc   = (__hip_bfloat16*)(w + 30 * MB);   // 2 MB
    __hip_bfloat16* Wt1    = (__hip_bfloat16*)(w + 32 * MB);   // 8 MB  [4096][1024]
    __hip_bfloat16* Wt2    = (__hip_bfloat16*)(w + 40 * MB);   // 8 MB  [1024][4096]
    float*          BiasQKVs = (float*)(w + 48 * MB);          // 12 KB
    float*          BiasKVc  = (float*)(w + 48 * MB + 65536);  // 8 KB
    __hip_bfloat16* QKV    = (__hip_bfloat16*)(w + 49 * MB);   // 24 MB
    __hip_bfloat16* Qc     = QKV;                               // 8 MB [4096][1024]
    __hip_bfloat16* KVc    = (__hip_bfloat16*)(w + 57 * MB);   // 16 MB [4096][2048]
    float*          Psplit = (float*)(w + 49 * MB);            // 32 MB [2][4096][1024]
    __hip_bfloat16* VtBuf  = (__hip_bfloat16*)(w + 73 * MB);   // 8 MB [2048][2048]
    __hip_bfloat16* Attn   = (__hip_bfloat16*)(w + 81 * MB);   // 8 MB
    float*          X1f    = (float*)(w + 97 * MB);            // 16 MB (dead after cross-LN)
    __hip_bfloat16* X1b    = (__hip_bfloat16*)(w + 113 * MB);  // 8 MB
    float*          X2f    = (float*)(w + 121 * MB);           // 16 MB
    __hip_bfloat16* X2b    = (__hip_bfloat16*)(w + 137 * MB);  // 8 MB
    __hip_bfloat16* H1     = (__hip_bfloat16*)(w + 145 * MB);  // 32 MB (FFN; scratch below)
    float*          FaO    = (float*)(w + 145 * MB);           // 16 MB self-flash partial O (dead before FFN)
    float*          FaL    = (float*)(w + 161 * MB);           // 256 KB self-flash partial l
    float*          P0     = Psplit;
    float*          P1     = Psplit + (size_t)MROWS * 1024;
    float*          P2     = (float*)(w + 0 * MB);             // reuses dead Xdec/Xenc (16 MB)
    float*          P3     = X1f;                              // reuses dead X1f (16 MB)
    const int NOVT = 1 << 30;

    // ---- prep (2 launches) ----
    cast2_k<<<8192, 256, 0, stream>>>(dec, enc, Xdec, Xenc);
    prep_w_k<<<16404, 256, 0, stream>>>(Wq_s, Wk_s, Wv_s, Wq_c, Wk_c, Wv_c, Wo_s, Wo_c,
                                        W1, W2, bq_s, bk_s, bv_s, bk_c, bv_c,
                                        WtQKVs, WtQc, WtKVc, WtOs, WtOc, Wt1, Wt2,
                                        BiasQKVs, BiasKVc);

    // ---- self attention ----
    gemm_bf16_k<<<dim3(24, 32), 256, 0, stream>>>(Xdec, WtQKVs, BiasQKVs, QKV, 3072, 1024, 0,
                                                  VtBuf, 2048);
    flash_attn<<<dim3(48, 32), 256, 0, stream>>>(QKV, 3072, 0, QKV, 3072, 1024, VtBuf, Attn, 1,
                                                 FaO, FaL);
    fa_combine_k<<<512, 256, 0, stream>>>(FaO, FaL, Attn);
    gemm_sk2_k<<<dim3(8, 32, 2), 256, 0, stream>>>(Attn, WtOs, Psplit, 1024, 1024);
    ln2_k<<<MROWS, 256, 0, stream>>>(dec, P0, P1, bo_s, g1, be1, X1f, X1b);

    // ---- cross attention ----
    gemm_pair_k<<<dim3(24, 32), 256, 0, stream>>>(X1b, WtQc, bq_c, Qc, 1024, 1024,
                                                  Xenc, WtKVc, BiasKVc, KVc, 2048, 1024,
                                                  VtBuf, 1024, 8);
    flash_attn<<<dim3(32, 32), 256, 0, stream>>>(Qc, 1024, 0, KVc, 2048, 0, VtBuf, Attn, 0,
                                                 nullptr, nullptr);
    gemm_sk2_k<<<dim3(8, 32, 2), 256, 0, stream>>>(Attn, WtOc, Psplit, 1024, 1024);
    ln2_k<<<MROWS, 256, 0, stream>>>(X1f, P0, P1, bo_c, g2, be2, X2f, X2b);

    // ---- FFN ----
    g256_k<<<dim3(16, 16), 512, 0, stream>>>(X2b, Wt1, b1, H1, 4096, 1024, 1,
                                             nullptr, NOVT);
    g256_sk4_k<<<dim3(4, 16, 4), 512, 0, stream>>>(H1, Wt2, P0, P1, P2, P3, 1024, 4096);
    ln4_k<<<MROWS, 256, 0, stream>>>(X2f, P0, P1, P2, P3, b2, g3, be3, (float*)d_out);
}

// Round 10
// 488.940 us; speedup vs baseline: 1.0744x; 1.0723x over previous
//
#include <hip/hip_runtime.h>
#include <hip/hip_bf16.h>

typedef __attribute__((ext_vector_type(8))) short short8;
typedef __attribute__((ext_vector_type(4))) short short4v;
typedef __attribute__((ext_vector_type(4))) float floatx4;

#define TDIM 2048
#define BDIM 2
#define MROWS (BDIM * TDIM)   // 4096

#define ASM_VMCNT0() __asm__ volatile("s_waitcnt vmcnt(0)" ::: "memory")
#define ASM_VMCNT2() __asm__ volatile("s_waitcnt vmcnt(2)" ::: "memory")
#define ASM_VMCNT4() __asm__ volatile("s_waitcnt vmcnt(4)" ::: "memory")
#define ASM_LGKM0()  __asm__ volatile("s_waitcnt lgkmcnt(0)" ::: "memory")
#define ASM_BARRIER() __asm__ volatile("s_barrier" ::: "memory")

// K=16 bf16 MFMA wrapper (device pass picks the real builtin).
__device__ __forceinline__ floatx4 mfma16(short4v a, short4v b, floatx4 c) {
#if defined(__HIP_DEVICE_COMPILE__)
#if __has_builtin(__builtin_amdgcn_mfma_f32_16x16x16bf16_1k)
    return __builtin_amdgcn_mfma_f32_16x16x16bf16_1k(a, b, c, 0, 0, 0);
#else
    short8 az = {a[0], a[1], a[2], a[3], 0, 0, 0, 0};
    short8 bz = {b[0], b[1], b[2], b[3], 0, 0, 0, 0};
    return __builtin_amdgcn_mfma_f32_16x16x32_bf16(az, bz, c, 0, 0, 0);
#endif
#else
    (void)a; (void)b;
    return c;
#endif
}

// async global->LDS, 16B per lane; LDS dest = wave-uniform base + lane*16
__device__ __forceinline__ void gload_lds16(const void* g, void* l) {
    __builtin_amdgcn_global_load_lds((const __attribute__((address_space(1))) void*)g,
                                     (__attribute__((address_space(3))) void*)l, 16, 0, 0);
}

__device__ __forceinline__ short bf16s(float x) {
    __hip_bfloat16 h = __float2bfloat16(x);
    return *(short*)&h;
}

__device__ __forceinline__ float bf2f(__hip_bfloat16 h) {
    return __bfloat162float(h);
}

// native 2^x through the COMPILER (hazard-safe), not inline asm
__device__ __forceinline__ float fexp2(float x) {
#if defined(__HIP_DEVICE_COMPILE__)
#if __has_builtin(__builtin_amdgcn_exp2f)
    return __builtin_amdgcn_exp2f(x);
#else
    return exp2f(x);
#endif
#else
    return x;
#endif
}

// ---------------------------------------------------------------------------
// Fused prep: dual cast fp32->bf16 (blocks 0..8191) + 10 weight transposes
// + 2 bias concats (blocks 8192..24595). One launch, one sync boundary.
__global__ __launch_bounds__(256) void prep_all_k(
    const float* __restrict__ dec, const float* __restrict__ enc,
    __hip_bfloat16* __restrict__ Xdec, __hip_bfloat16* __restrict__ Xenc,
    const float* __restrict__ Wq_s, const float* __restrict__ Wk_s, const float* __restrict__ Wv_s,
    const float* __restrict__ Wq_c, const float* __restrict__ Wk_c, const float* __restrict__ Wv_c,
    const float* __restrict__ Wo_s, const float* __restrict__ Wo_c,
    const float* __restrict__ W1, const float* __restrict__ W2,
    const float* __restrict__ bq_s, const float* __restrict__ bk_s, const float* __restrict__ bv_s,
    const float* __restrict__ bk_c, const float* __restrict__ bv_c,
    __hip_bfloat16* __restrict__ WtQKVs, __hip_bfloat16* __restrict__ WtQc,
    __hip_bfloat16* __restrict__ WtKVc, __hip_bfloat16* __restrict__ WtOs,
    __hip_bfloat16* __restrict__ WtOc, __hip_bfloat16* __restrict__ Wt1,
    __hip_bfloat16* __restrict__ Wt2,
    float* __restrict__ BiasQKVs, float* __restrict__ BiasKVc) {
    __shared__ float tile[32][33];
    const int blk = blockIdx.x;
    if (blk < 8192) {  // cast path (no LDS)
        const float* in = (blk < 4096) ? dec : enc;
        __hip_bfloat16* out = (blk < 4096) ? Xdec : Xenc;
        const size_t base = (size_t)(blk & 4095) * 1024 + threadIdx.x * 4;
        float4 v = *(const float4*)&in[base];
        out[base + 0] = __float2bfloat16(v.x);
        out[base + 1] = __float2bfloat16(v.y);
        out[base + 2] = __float2bfloat16(v.z);
        out[base + 3] = __float2bfloat16(v.w);
        return;
    }
    const int t = blk - 8192;
    const int tx = threadIdx.x & 31, ty = threadIdx.x >> 5;
    const float* s;
    __hip_bfloat16* d;
    int R, C, c0, r0;
    if (t < 6144) {  // per-head stacks: R=1024, C=64, 16 slabs, 64 tiles/slab
        const int seg = t >> 10, tl = t & 1023;
        if (seg == 0) { s = Wq_s; d = WtQKVs; }
        else if (seg == 1) { s = Wk_s; d = WtQKVs + 1048576; }
        else if (seg == 2) { s = Wv_s; d = WtQKVs + 2097152; }
        else if (seg == 3) { s = Wq_c; d = WtQc; }
        else if (seg == 4) { s = Wk_c; d = WtKVc; }
        else { s = Wv_c; d = WtKVc + 1048576; }
        const int slab = tl >> 6, rem = tl & 63;
        s += (size_t)slab * 65536; d += (size_t)slab * 65536;
        R = 1024; C = 64; c0 = (rem & 1) * 32; r0 = (rem >> 1) * 32;
    } else if (t < 8192) {  // Wo_s / Wo_c: 1024x1024
        const int rem = (t - 6144) & 1023;
        s = (t < 7168) ? Wo_s : Wo_c;
        d = (t < 7168) ? WtOs : WtOc;
        R = 1024; C = 1024; c0 = (rem & 31) * 32; r0 = (rem >> 5) * 32;
    } else if (t < 12288) {  // W1: R=1024 C=4096
        const int rem = t - 8192;
        s = W1; d = Wt1;
        R = 1024; C = 4096; c0 = (rem & 127) * 32; r0 = (rem >> 7) * 32;
    } else if (t < 16384) {  // W2: R=4096 C=1024
        const int rem = t - 12288;
        s = W2; d = Wt2;
        R = 4096; C = 1024; c0 = (rem & 31) * 32; r0 = (rem >> 5) * 32;
    } else if (t < 16396) {  // concat3 -> BiasQKVs
        const int i = (t - 16384) * 256 + threadIdx.x;
        BiasQKVs[i] = (i < 1024) ? bq_s[i] : (i < 2048 ? bk_s[i - 1024] : bv_s[i - 2048]);
        return;
    } else {  // concat2 -> BiasKVc
        const int i = (t - 16396) * 256 + threadIdx.x;
        BiasKVc[i] = (i < 1024) ? bk_c[i] : bv_c[i - 1024];
        return;
    }
#pragma unroll
    for (int i = 0; i < 4; ++i)
        tile[ty + 8 * i][tx] = s[(size_t)(r0 + ty + 8 * i) * C + c0 + tx];
    __syncthreads();
#pragma unroll
    for (int i = 0; i < 4; ++i)
        d[(size_t)(c0 + ty + 8 * i) * R + r0 + tx] = __float2bfloat16(tile[tx][ty + 8 * i]);
}

// ---------------------------------------------------------------------------
// 128x128 4-wave GEMM core. Pf (split-K partials) is now bf16: halves the
// partial write+read HBM traffic (precision: partials O(0.3-2), bf16 rounding
// ~2^-9 relative -- well under the 0.105 absmax budget).
__device__ __forceinline__ void gemm_core(
    const __hip_bfloat16* __restrict__ A, const __hip_bfloat16* __restrict__ Bt,
    int K, int kBeg, int kLen,
    const float* __restrict__ bias, __hip_bfloat16* __restrict__ C, int ldc,
    __hip_bfloat16* __restrict__ Pf,
    __hip_bfloat16* __restrict__ Vt, int vt_col0, int relu,
    int m0, int n0, __hip_bfloat16* sm) {
    const int tid = threadIdx.x;
    const int lane = tid & 63, wave = tid >> 6;
    const int quad = lane >> 4, l16 = lane & 15;
    const int wm = (wave >> 1) * 64, wn = (wave & 1) * 64;
    const int lrow = lane >> 3;
    const int gsw = (((lane & 7) ^ lrow)) * 8;  // swizzled source column (elems)
    const int sw7 = l16 & 7;                    // reader swizzle key (row&7)
    const __hip_bfloat16* gA = A + (size_t)(m0 + wave * 32 + lrow) * K + kBeg + gsw;
    const __hip_bfloat16* gB = Bt + (size_t)(n0 + wave * 32 + lrow) * K + kBeg + gsw;
    __hip_bfloat16* lA = sm + wave * 2048;
    __hip_bfloat16* lB = sm + 16384 + wave * 2048;
    floatx4 acc[4][4] = {};
    const int T = kLen >> 6;
#pragma unroll
    for (int i = 0; i < 4; ++i) {
        gload_lds16(gA + (size_t)i * 8 * K, lA + i * 512);
        gload_lds16(gB + (size_t)i * 8 * K, lB + i * 512);
    }
    for (int t = 0; t < T; ++t) {
        ASM_VMCNT0();
        ASM_BARRIER();
        if (t + 1 < T) {
            const int koff = (t + 1) << 6;
            const int b = ((t + 1) & 1) * 8192;
#pragma unroll
            for (int i = 0; i < 4; ++i) {
                gload_lds16(gA + (size_t)i * 8 * K + koff, lA + b + i * 512);
                gload_lds16(gB + (size_t)i * 8 * K + koff, lB + b + i * 512);
            }
        }
        const __hip_bfloat16* cA = sm + (t & 1) * 8192;
        const __hip_bfloat16* cB = sm + 16384 + (t & 1) * 8192;
#pragma unroll
        for (int kc = 0; kc < 2; ++kc) {
            short8 af[4], bfr[4];
#pragma unroll
            for (int i = 0; i < 4; ++i) {
                af[i] = *(const short8*)&cA[(wm + i * 16 + l16) * 64 +
                                            (((kc * 4 + quad) ^ sw7) * 8)];
                bfr[i] = *(const short8*)&cB[(wn + i * 16 + l16) * 64 +
                                             (((kc * 4 + quad) ^ sw7) * 8)];
            }
#pragma unroll
            for (int mi = 0; mi < 4; ++mi)
#pragma unroll
                for (int ni = 0; ni < 4; ++ni)
                    acc[mi][ni] =
                        __builtin_amdgcn_mfma_f32_16x16x32_bf16(af[mi], bfr[ni], acc[mi][ni], 0, 0, 0);
        }
    }
    // epilogue
    if (Pf) {
#pragma unroll
        for (int ni = 0; ni < 4; ++ni) {
            const int col = n0 + wn + ni * 16 + l16;
#pragma unroll
            for (int mi = 0; mi < 4; ++mi)
#pragma unroll
                for (int r = 0; r < 4; ++r) {
                    const int row = m0 + wm + mi * 16 + quad * 4 + r;
                    Pf[(size_t)row * ldc + col] = __float2bfloat16(acc[mi][ni][r]);
                }
        }
    } else {
        const bool toVt = (n0 >= vt_col0);
#pragma unroll
        for (int ni = 0; ni < 4; ++ni) {
            const int col = n0 + wn + ni * 16 + l16;
            const float bv = bias[col];
#pragma unroll
            for (int mi = 0; mi < 4; ++mi) {
                const int row0 = m0 + wm + mi * 16 + quad * 4;
                if (toVt) {
                    const int b = row0 >> 11, t0 = row0 & (TDIM - 1);
                    short4v pk;
#pragma unroll
                    for (int r = 0; r < 4; ++r) pk[r] = bf16s(acc[mi][ni][r] + bv);
                    *(short4v*)&Vt[((size_t)(b * 1024 + (col - vt_col0)) << 11) + t0] = pk;
                } else {
#pragma unroll
                    for (int r = 0; r < 4; ++r) {
                        float v = acc[mi][ni][r] + bv;
                        if (relu) v = fmaxf(v, 0.f);
                        C[(size_t)(row0 + r) * ldc + col] = __float2bfloat16(v);
                    }
                }
            }
        }
    }
}

__global__ __launch_bounds__(256) void gemm_bf16_k(const __hip_bfloat16* __restrict__ A,
                                                   const __hip_bfloat16* __restrict__ Bt,
                                                   const float* __restrict__ bias,
                                                   __hip_bfloat16* __restrict__ C,
                                                   int N, int K, int relu,
                                                   __hip_bfloat16* __restrict__ Vt, int vt_col0) {
    __shared__ __hip_bfloat16 sm[2 * 128 * 64 * 2];
    gemm_core(A, Bt, K, 0, K, bias, C, N, nullptr, Vt, vt_col0, relu,
              blockIdx.y * 128, blockIdx.x * 128, sm);
}

__global__ __launch_bounds__(256) void gemm_sk2_k(const __hip_bfloat16* __restrict__ A,
                                                  const __hip_bfloat16* __restrict__ Bt,
                                                  __hip_bfloat16* __restrict__ Pf, int N, int K) {
    __shared__ __hip_bfloat16 sm[2 * 128 * 64 * 2];
    const int z = blockIdx.z;
    gemm_core(A, Bt, K, z * (K >> 1), K >> 1, nullptr, nullptr, N,
              Pf + (size_t)z * MROWS * N, nullptr, 1 << 30, 0,
              blockIdx.y * 128, blockIdx.x * 128, sm);
}

__global__ __launch_bounds__(256) void gemm_pair_k(
    const __hip_bfloat16* __restrict__ A1, const __hip_bfloat16* __restrict__ Bt1,
    const float* __restrict__ bias1, __hip_bfloat16* __restrict__ C1, int N1, int K1,
    const __hip_bfloat16* __restrict__ A2, const __hip_bfloat16* __restrict__ Bt2,
    const float* __restrict__ bias2, __hip_bfloat16* __restrict__ C2, int N2, int K2,
    __hip_bfloat16* __restrict__ Vt2, int vtc2, int nx1) {
    __shared__ __hip_bfloat16 sm[2 * 128 * 64 * 2];
    if ((int)blockIdx.x < nx1)
        gemm_core(A1, Bt1, K1, 0, K1, bias1, C1, N1, nullptr, nullptr, 1 << 30, 0,
                  blockIdx.y * 128, blockIdx.x * 128, sm);
    else
        gemm_core(A2, Bt2, K2, 0, K2, bias2, C2, N2, nullptr, Vt2, vtc2, 0,
                  blockIdx.y * 128, (blockIdx.x - nx1) * 128, sm);
}

// ---------------------------------------------------------------------------
// 256x256 8-wave GEMM core, deep-prefetch double-buffer (exact-fill FFN GEMMs).
// Pf partials now bf16.
__device__ __forceinline__ void gemm256_core(
    const __hip_bfloat16* __restrict__ A, const __hip_bfloat16* __restrict__ Bt,
    int K, int kBeg, int kLen,
    const float* __restrict__ bias, __hip_bfloat16* __restrict__ C, int ldc,
    __hip_bfloat16* __restrict__ Pf,
    __hip_bfloat16* __restrict__ Vt, int vt_col0, int relu,
    int m0, int n0, __hip_bfloat16* sm) {
    const int tid = threadIdx.x;
    const int lane = tid & 63, wave = tid >> 6;
    const int quad = lane >> 4, l16 = lane & 15;
    const int wm = (wave >> 2) * 128, wn = (wave & 3) * 64;
    const int lrow = lane >> 3;
    const int gsw = ((lane & 7) ^ lrow) * 8;
    const int sw7 = l16 & 7;
    const __hip_bfloat16* aSrc = A + (size_t)(m0 + wave * 16 + lrow) * K + kBeg + gsw;
    const __hip_bfloat16* bSrc = Bt + (size_t)(n0 + wave * 16 + lrow) * K + kBeg + gsw;
    floatx4 acc[8][4] = {};
    const int T = kLen >> 6;
#pragma unroll
    for (int h = 0; h < 2; ++h)
#pragma unroll
        for (int j = 0; j < 2; ++j) {
            const size_t ro = (size_t)(h * 128 + j * 8);
            gload_lds16(aSrc + ro * K, sm + (h * 128 + wave * 16 + j * 8) * 64);
            gload_lds16(bSrc + ro * K, sm + 16384 + (h * 128 + wave * 16 + j * 8) * 64);
        }
    for (int t = 0; t < T; ++t) {
        const int c = t & 1;
        const __hip_bfloat16* cA = sm + c * 32768;
        const __hip_bfloat16* cB = cA + 16384;
        ASM_VMCNT0();
        ASM_BARRIER();
        if (t + 1 < T) {
            __hip_bfloat16* dst = sm + (1 - c) * 32768;
            const size_t nko = (size_t)(t + 1) * 64;
#pragma unroll
            for (int h = 0; h < 2; ++h)
#pragma unroll
                for (int j = 0; j < 2; ++j) {
                    const size_t ro = (size_t)(h * 128 + j * 8);
                    gload_lds16(aSrc + ro * K + nko, dst + (h * 128 + wave * 16 + j * 8) * 64);
                    gload_lds16(bSrc + ro * K + nko, dst + 16384 + (h * 128 + wave * 16 + j * 8) * 64);
                }
        }
#pragma unroll
        for (int kh = 0; kh < 2; ++kh) {
            const int gk = ((kh * 4 + quad) ^ sw7) * 8;
            short8 af[4], bfr[4];
#pragma unroll
            for (int i = 0; i < 4; ++i) {
                af[i] = *(const short8*)&cA[(wm + i * 16 + l16) * 64 + gk];
                bfr[i] = *(const short8*)&cB[(wn + i * 16 + l16) * 64 + gk];
            }
            __builtin_amdgcn_s_setprio(1);
#pragma unroll
            for (int mi = 0; mi < 4; ++mi)
#pragma unroll
                for (int ni = 0; ni < 4; ++ni)
                    acc[mi][ni] = __builtin_amdgcn_mfma_f32_16x16x32_bf16(af[mi], bfr[ni], acc[mi][ni], 0, 0, 0);
            __builtin_amdgcn_s_setprio(0);
#pragma unroll
            for (int i = 0; i < 4; ++i)
                af[i] = *(const short8*)&cA[(wm + 64 + i * 16 + l16) * 64 + gk];
            __builtin_amdgcn_s_setprio(1);
#pragma unroll
            for (int mi = 0; mi < 4; ++mi)
#pragma unroll
                for (int ni = 0; ni < 4; ++ni)
                    acc[4 + mi][ni] = __builtin_amdgcn_mfma_f32_16x16x32_bf16(af[mi], bfr[ni], acc[4 + mi][ni], 0, 0, 0);
            __builtin_amdgcn_s_setprio(0);
        }
    }
    // epilogue
    if (Pf) {
#pragma unroll
        for (int ni = 0; ni < 4; ++ni) {
            const int col = n0 + wn + ni * 16 + l16;
#pragma unroll
            for (int mi = 0; mi < 8; ++mi)
#pragma unroll
                for (int r = 0; r < 4; ++r) {
                    const int row = m0 + wm + mi * 16 + quad * 4 + r;
                    Pf[(size_t)row * ldc + col] = __float2bfloat16(acc[mi][ni][r]);
                }
        }
    } else {
        const bool toVt = (n0 >= vt_col0);
#pragma unroll
        for (int ni = 0; ni < 4; ++ni) {
            const int col = n0 + wn + ni * 16 + l16;
            const float bv = bias[col];
#pragma unroll
            for (int mi = 0; mi < 8; ++mi) {
                const int row0 = m0 + wm + mi * 16 + quad * 4;
                if (toVt) {
                    const int b = row0 >> 11, t0 = row0 & (TDIM - 1);
                    short4v pk;
#pragma unroll
                    for (int r = 0; r < 4; ++r) pk[r] = bf16s(acc[mi][ni][r] + bv);
                    *(short4v*)&Vt[((size_t)(b * 1024 + (col - vt_col0)) << 11) + t0] = pk;
                } else {
#pragma unroll
                    for (int r = 0; r < 4; ++r) {
                        float v = acc[mi][ni][r] + bv;
                        if (relu) v = fmaxf(v, 0.f);
                        C[(size_t)(row0 + r) * ldc + col] = __float2bfloat16(v);
                    }
                }
            }
        }
    }
}

__global__ __launch_bounds__(512, 2) void g256_k(const __hip_bfloat16* __restrict__ A,
                                                 const __hip_bfloat16* __restrict__ Bt,
                                                 const float* __restrict__ bias,
                                                 __hip_bfloat16* __restrict__ C,
                                                 int N, int K, int relu,
                                                 __hip_bfloat16* __restrict__ Vt, int vt_col0) {
    __shared__ __hip_bfloat16 sm[65536];  // 128 KiB
    gemm256_core(A, Bt, K, 0, K, bias, C, N, nullptr, Vt, vt_col0, relu,
                 blockIdx.y * 256, blockIdx.x * 256, sm);
}

// FFN2 split-K 4: 4 bf16 partial outputs (combined by ln4_k). 256 blocks.
__global__ __launch_bounds__(512, 2) void g256_sk4_k(const __hip_bfloat16* __restrict__ A,
                                                     const __hip_bfloat16* __restrict__ Bt,
                                                     __hip_bfloat16* __restrict__ Pf0,
                                                     __hip_bfloat16* __restrict__ Pf1,
                                                     __hip_bfloat16* __restrict__ Pf2,
                                                     __hip_bfloat16* __restrict__ Pf3,
                                                     int N, int K) {
    __shared__ __hip_bfloat16 sm[65536];
    const int z = blockIdx.z;
    __hip_bfloat16* pf = (z == 0) ? Pf0 : (z == 1) ? Pf1 : (z == 2) ? Pf2 : Pf3;
    gemm256_core(A, Bt, K, z * (K >> 2), K >> 2, nullptr, nullptr, N, pf,
                 nullptr, 1 << 30, 0, blockIdx.y * 256, blockIdx.x * 256, sm);
}

// ---------------------------------------------------------------------------
// Flash attention, register-resident P. Processes k-tiles [tBeg, tEnd).
// k-loop unrolled x2 so the LDS double-buffer offset (CB/NB) is a literal
// (ds_read offset-immediate folding). Split K/V waits: per wave DMAs are
// issued K,K,V,V; tile top waits vmcnt(2) (K ready, V in flight), QK^T+exp
// overlap V arrival; vmcnt(4) before PV (V ready, next tile's 4 prefetch
// DMAs stay in flight). Invariant: exactly 4 DMAs outstanding at tile top
// (last tile re-stages itself to keep counts uniform).
__device__ __forceinline__ void flash_one(
    const __hip_bfloat16* __restrict__ Q, int ldq, int qc0,
    const __hip_bfloat16* __restrict__ Kp, int ldk,
    const __hip_bfloat16* __restrict__ Vp,
    __hip_bfloat16* __restrict__ O, int causal, int q0, size_t rowb, int h,
    int tBeg, int tEnd, float* __restrict__ Opart, float* __restrict__ lpart,
    __hip_bfloat16* sK, __hip_bfloat16* sV) {
    const int tid = threadIdx.x, lane = tid & 63, wave = tid >> 6;
    const int quad = lane >> 4, l16 = lane & 15;
    const int lrow = lane >> 3;
    const int gsw = ((lane & 7) ^ lrow) * 8;  // DMA swizzled source col (elems)
    const int sw7 = l16 & 7;
    short8 qf[2];
    {
        const __hip_bfloat16* qp = Q + (rowb + q0 + wave * 16 + l16) * (size_t)ldq + qc0 + h * 64;
        const float qs = 0.18033688f;  // 0.125 * log2(e)
        short8 r0 = *(const short8*)(qp + quad * 8);
        short8 r1 = *(const short8*)(qp + 32 + quad * 8);
#pragma unroll
        for (int j = 0; j < 8; ++j) {
            qf[0][j] = bf16s(__uint_as_float(((unsigned)(unsigned short)r0[j]) << 16) * qs);
            qf[1][j] = bf16s(__uint_as_float(((unsigned)(unsigned short)r1[j]) << 16) * qs);
        }
    }
    short4v ones4;
#pragma unroll
    for (int j = 0; j < 4; ++j) ones4[j] = (short)0x3F80;  // bf16 1.0
    floatx4 Ot[4] = {};  // Ot[dt][r] = O[q=..+l16][d=dt*16+quad*4+r]
    floatx4 accl = {};
    const int nDiag = q0 >> 6;
    const int rb = wave * 16;
    ASM_LGKM0();
    ASM_BARRIER();
    {   // prologue stage: K,K then V,V (order matters for counted waits)
        const int s0 = tBeg << 6, pb = (tBeg & 1) * 4096;
        gload_lds16(&Kp[(rowb + s0 + rb + lrow) * (size_t)ldk + gsw], &sK[pb + rb * 64]);
        gload_lds16(&Kp[(rowb + s0 + rb + 8 + lrow) * (size_t)ldk + gsw], &sK[pb + (rb + 8) * 64]);
        gload_lds16(&Vp[(size_t)(rb + lrow) * TDIM + s0 + gsw], &sV[pb + rb * 64]);
        gload_lds16(&Vp[(size_t)(rb + 8 + lrow) * TDIM + s0 + gsw], &sV[pb + (rb + 8) * 64]);
    }

#define FA_TILE(TT, CB, NB)                                                              \
    do {                                                                                 \
        const int tt = (TT);                                                             \
        ASM_VMCNT2();  /* this tile's K landed (V may still be in flight) */             \
        ASM_BARRIER();                                                                   \
        {   /* prefetch next tile (clamped on last -> uniform wait counts) */            \
            const int nx = (tt + 1 < tEnd) ? tt + 1 : tt;                                \
            const int s1 = nx << 6;                                                      \
            gload_lds16(&Kp[(rowb + s1 + rb + lrow) * (size_t)ldk + gsw],                \
                        &sK[(NB) + rb * 64]);                                            \
            gload_lds16(&Kp[(rowb + s1 + rb + 8 + lrow) * (size_t)ldk + gsw],            \
                        &sK[(NB) + (rb + 8) * 64]);                                      \
            gload_lds16(&Vp[(size_t)(rb + lrow) * TDIM + s1 + gsw],                      \
                        &sV[(NB) + rb * 64]);                                            \
            gload_lds16(&Vp[(size_t)(rb + 8 + lrow) * TDIM + s1 + gsw],                  \
                        &sV[(NB) + (rb + 8) * 64]);                                      \
        }                                                                                \
        floatx4 Sf[4] = {};                                                              \
        _Pragma("unroll") for (int st = 0; st < 4; ++st) {                               \
            short8 b0 = *(const short8*)&sK[(CB) + (st * 16 + l16) * 64 +                \
                                            ((quad ^ sw7) * 8)];                         \
            short8 b1 = *(const short8*)&sK[(CB) + (st * 16 + l16) * 64 +                \
                                            (((4 + quad) ^ sw7) * 8)];                   \
            Sf[st] = __builtin_amdgcn_mfma_f32_16x16x32_bf16(b0, qf[0], Sf[st], 0, 0, 0);\
            Sf[st] = __builtin_amdgcn_mfma_f32_16x16x32_bf16(b1, qf[1], Sf[st], 0, 0, 0);\
        }                                                                                \
        _Pragma("unroll") for (int st = 0; st < 4; ++st)                                 \
            _Pragma("unroll") for (int r = 0; r < 4; ++r) Sf[st][r] = fexp2(Sf[st][r]);  \
        if (causal && tt == nDiag) {                                                     \
            const int qr = wave * 16 + l16;                                              \
            _Pragma("unroll") for (int st = 0; st < 4; ++st)                             \
                _Pragma("unroll") for (int r = 0; r < 4; ++r)                            \
                    if (st * 16 + quad * 4 + r > qr) Sf[st][r] = 0.f;                    \
        }                                                                                \
        short4v pf[4];                                                                   \
        _Pragma("unroll") for (int st = 0; st < 4; ++st)                                 \
            _Pragma("unroll") for (int r = 0; r < 4; ++r) pf[st][r] = bf16s(Sf[st][r]);  \
        ASM_VMCNT4();  /* this tile's V landed (next tile's 4 DMAs in flight) */         \
        ASM_BARRIER();                                                                   \
        _Pragma("unroll") for (int st = 0; st < 4; ++st) accl = mfma16(ones4, pf[st], accl); \
        _Pragma("unroll") for (int dt = 0; dt < 4; ++dt)                                 \
            _Pragma("unroll") for (int st = 0; st < 4; ++st) {                           \
                short4v av = *(const short4v*)&sV[(CB) + (dt * 16 + l16) * 64 +          \
                                                 (((st * 2 + (quad >> 1)) ^ sw7) * 8) +  \
                                                 (quad & 1) * 4];                        \
                Ot[dt] = mfma16(av, pf[st], Ot[dt]);                                     \
            }                                                                            \
    } while (0)

    int t = tBeg;
    if (t & 1) { FA_TILE(t, 4096, 0); ++t; }
    for (; t + 1 < tEnd; t += 2) {
        FA_TILE(t, 0, 4096);
        FA_TILE(t + 1, 4096, 0);
    }
    if (t < tEnd) FA_TILE(t, 0, 4096);
#undef FA_TILE

    if (Opart) {
        const int qrow = wave * 16 + l16;
#pragma unroll
        for (int dt = 0; dt < 4; ++dt)
            *(floatx4*)&Opart[qrow * 64 + dt * 16 + quad * 4] = Ot[dt];
        if (quad == 0) lpart[qrow] = accl[0];
    } else {
        const float inv = 1.0f / accl[0];
        __hip_bfloat16* op = O + (rowb + q0 + wave * 16 + l16) * (size_t)1024 + h * 64 + quad * 4;
#pragma unroll
        for (int dt = 0; dt < 4; ++dt) {
            short4v pk;
#pragma unroll
            for (int r = 0; r < 4; ++r) pk[r] = bf16s(Ot[dt][r] * inv);
            *(short4v*)(op + dt * 16) = pk;
        }
    }
}

// XCD-aware remap (T1): all q-blocks of one (b,h) land on one XCD so its
// K/V head is fetched into that XCD's L2 exactly once. Linear wgid w:
// bh = (w&7)*4 + ((w>>3)&3), bx = w>>5. Bijective for gy=32, gx in {32,48}.
// causal=1: grid (48,32):
//   bx 0..31  -> q-tiles i=16+(bx>>1) split into half k-ranges hh=bx&1 (partials)
//   bx 32..47 -> q-tiles i=47-bx unsplit (direct output)
// causal=0: grid (32,32), one full q-tile per block.
__global__ __launch_bounds__(256) void flash_attn(const __hip_bfloat16* __restrict__ Q, int ldq, int qc0,
                                                  const __hip_bfloat16* __restrict__ K, int ldk, int kc0,
                                                  const __hip_bfloat16* __restrict__ Vt,
                                                  __hip_bfloat16* __restrict__ O, int causal,
                                                  float* __restrict__ Opart,
                                                  float* __restrict__ lpart) {
    __shared__ __hip_bfloat16 sK[2 * 64 * 64];
    __shared__ __hip_bfloat16 sV[2 * 64 * 64];
    const int w = (int)blockIdx.y * (int)gridDim.x + (int)blockIdx.x;
    const int bh = (w & 7) * 4 + ((w >> 3) & 3);
    const int bx = w >> 5;
    const int b = bh >> 4, h = bh & 15;
    const size_t rowb = (size_t)b * TDIM;
    const __hip_bfloat16* Kp = K + kc0 + h * 64;
    const __hip_bfloat16* Vp = Vt + ((size_t)(b * 1024 + h * 64) << 11);
    if (causal) {
        if (bx < 32) {
            const int i = 16 + (bx >> 1), hh = bx & 1;
            const int n = i + 1, n2 = n >> 1;
            const int p = bh * 16 + (i - 16);
            float* Op = Opart + (size_t)p * 8192 + hh * 4096;
            float* lp = lpart + p * 128 + hh * 64;
            flash_one(Q, ldq, qc0, Kp, ldk, Vp, O, 1, i * 64, rowb, h,
                      hh ? n2 : 0, hh ? n : n2, Op, lp, sK, sV);
        } else {
            const int i = 47 - bx;
            flash_one(Q, ldq, qc0, Kp, ldk, Vp, O, 1, i * 64, rowb, h,
                      0, i + 1, nullptr, nullptr, sK, sV);
        }
    } else {
        flash_one(Q, ldq, qc0, Kp, ldk, Vp, O, 0, bx * 64, rowb, h,
                  0, TDIM >> 6, nullptr, nullptr, sK, sV);
    }
}

// combine split-k flash partials: O = (O0+O1)/(l0+l1). grid 512 blocks (causal).
__global__ __launch_bounds__(256) void fa_combine_k(const float* __restrict__ Opart,
                                                    const float* __restrict__ lpart,
                                                    __hip_bfloat16* __restrict__ O) {
    const int p = blockIdx.x;            // = bh*16 + (i-16)
    const int bh = p >> 4, i = (p & 15) + 16;
    const int b = bh >> 4, h = bh & 15;
    const int tid = threadIdx.x;
    const int q = tid >> 2, dseg = (tid & 3) * 16;
    const float* O0 = Opart + (size_t)p * 8192;
    const float* O1 = O0 + 4096;
    const float inv = 1.f / (lpart[p * 128 + q] + lpart[p * 128 + 64 + q]);
    __hip_bfloat16* op = O + ((size_t)(b * TDIM) + i * 64 + q) * 1024 + h * 64 + dseg;
#pragma unroll
    for (int j = 0; j < 4; ++j) {
        floatx4 a = *(const floatx4*)&O0[q * 64 + dseg + j * 4];
        floatx4 c = *(const floatx4*)&O1[q * 64 + dseg + j * 4];
        short4v pk;
#pragma unroll
        for (int r = 0; r < 4; ++r) pk[r] = bf16s((a[r] + c[r]) * inv);
        *(short4v*)(op + j * 4) = pk;
    }
}

// ---------------------------------------------------------------------------
// LayerNorm with fused split-K reduction: delta = d0 + d1 + biasN (bf16 partials).
__global__ __launch_bounds__(256) void ln2_k(const float* __restrict__ resid,
                                             const __hip_bfloat16* __restrict__ d0,
                                             const __hip_bfloat16* __restrict__ d1,
                                             const float* __restrict__ biasN,
                                             const float* __restrict__ gamma,
                                             const float* __restrict__ beta,
                                             float* __restrict__ outf,
                                             __hip_bfloat16* __restrict__ outb) {
    const int row = blockIdx.x, tid = threadIdx.x;
    const size_t base = (size_t)row * 1024;
    float x[4], s = 0.f, sq = 0.f;
#pragma unroll
    for (int i = 0; i < 4; ++i) {
        const int c = tid + 256 * i;
        x[i] = resid[base + c] + bf2f(d0[base + c]) + bf2f(d1[base + c]) + biasN[c];
        s += x[i];
        sq += x[i] * x[i];
    }
#pragma unroll
    for (int off = 32; off > 0; off >>= 1) {
        s += __shfl_down(s, off);
        sq += __shfl_down(sq, off);
    }
    __shared__ float red[8];
    if ((tid & 63) == 0) {
        red[tid >> 6] = s;
        red[4 + (tid >> 6)] = sq;
    }
    __syncthreads();
    const float S = red[0] + red[1] + red[2] + red[3];
    const float Q2 = red[4] + red[5] + red[6] + red[7];
    const float mean = S * (1.f / 1024.f);
    const float var = Q2 * (1.f / 1024.f) - mean * mean;
    const float rstd = rsqrtf(var + 1e-5f);
#pragma unroll
    for (int i = 0; i < 4; ++i) {
        const int c = tid + 256 * i;
        const float y = (x[i] - mean) * rstd * gamma[c] + beta[c];
        outf[base + c] = y;
        if (outb) outb[base + c] = __float2bfloat16(y);
    }
}

// final LayerNorm: delta = d0+d1+d2+d3 + biasN (bf16 partials), f32 output only.
__global__ __launch_bounds__(256) void ln4_k(const float* __restrict__ resid,
                                             const __hip_bfloat16* __restrict__ d0,
                                             const __hip_bfloat16* __restrict__ d1,
                                             const __hip_bfloat16* __restrict__ d2,
                                             const __hip_bfloat16* __restrict__ d3,
                                             const float* __restrict__ biasN,
                                             const float* __restrict__ gamma,
                                             const float* __restrict__ beta,
                                             float* __restrict__ outf) {
    const int row = blockIdx.x, tid = threadIdx.x;
    const size_t base = (size_t)row * 1024;
    float x[4], s = 0.f, sq = 0.f;
#pragma unroll
    for (int i = 0; i < 4; ++i) {
        const int c = tid + 256 * i;
        x[i] = resid[base + c] + bf2f(d0[base + c]) + bf2f(d1[base + c]) +
               bf2f(d2[base + c]) + bf2f(d3[base + c]) + biasN[c];
        s += x[i];
        sq += x[i] * x[i];
    }
#pragma unroll
    for (int off = 32; off > 0; off >>= 1) {
        s += __shfl_down(s, off);
        sq += __shfl_down(sq, off);
    }
    __shared__ float red[8];
    if ((tid & 63) == 0) {
        red[tid >> 6] = s;
        red[4 + (tid >> 6)] = sq;
    }
    __syncthreads();
    const float S = red[0] + red[1] + red[2] + red[3];
    const float Q2 = red[4] + red[5] + red[6] + red[7];
    const float mean = S * (1.f / 1024.f);
    const float var = Q2 * (1.f / 1024.f) - mean * mean;
    const float rstd = rsqrtf(var + 1e-5f);
#pragma unroll
    for (int i = 0; i < 4; ++i) {
        const int c = tid + 256 * i;
        outf[base + c] = (x[i] - mean) * rstd * gamma[c] + beta[c];
    }
}

// ---------------------------------------------------------------------------
extern "C" void kernel_launch(void* const* d_in, const int* in_sizes, int n_in,
                              void* d_out, int out_size, void* d_ws, size_t ws_size,
                              hipStream_t stream) {
    (void)in_sizes; (void)n_in; (void)out_size; (void)ws_size;
    const float* dec  = (const float*)d_in[0];
    const float* enc  = (const float*)d_in[1];
    const float* Wq_s = (const float*)d_in[2];
    const float* bq_s = (const float*)d_in[3];
    const float* Wk_s = (const float*)d_in[4];
    const float* bk_s = (const float*)d_in[5];
    const float* Wv_s = (const float*)d_in[6];
    const float* bv_s = (const float*)d_in[7];
    const float* Wo_s = (const float*)d_in[8];
    const float* bo_s = (const float*)d_in[9];
    const float* Wq_c = (const float*)d_in[10];
    const float* bq_c = (const float*)d_in[11];
    const float* Wk_c = (const float*)d_in[12];
    const float* bk_c = (const float*)d_in[13];
    const float* Wv_c = (const float*)d_in[14];
    const float* bv_c = (const float*)d_in[15];
    const float* Wo_c = (const float*)d_in[16];
    const float* bo_c = (const float*)d_in[17];
    const float* W1   = (const float*)d_in[18];
    const float* b1   = (const float*)d_in[19];
    const float* W2   = (const float*)d_in[20];
    const float* b2   = (const float*)d_in[21];
    const float* g1   = (const float*)d_in[22];
    const float* be1  = (const float*)d_in[23];
    const float* g2   = (const float*)d_in[24];
    const float* be2  = (const float*)d_in[25];
    const float* g3   = (const float*)d_in[26];
    const float* be3  = (const float*)d_in[27];

    char* w = (char*)d_ws;
    const size_t MB = 1ull << 20;
    __hip_bfloat16* Xdec   = (__hip_bfloat16*)(w + 0 * MB);    // 8 MB (dead after QKV)
    __hip_bfloat16* Xenc   = (__hip_bfloat16*)(w + 8 * MB);    // 8 MB (dead after pair)
    __hip_bfloat16* WtQKVs = (__hip_bfloat16*)(w + 16 * MB);   // 6 MB  [3072][1024]
    __hip_bfloat16* WtOs   = (__hip_bfloat16*)(w + 22 * MB);   // 2 MB
    __hip_bfloat16* WtQc   = (__hip_bfloat16*)(w + 24 * MB);   // 2 MB
    __hip_bfloat16* WtKVc  = (__hip_bfloat16*)(w + 26 * MB);   // 4 MB  [2048][1024]
    __hip_bfloat16* WtOc   = (__hip_bfloat16*)(w + 30 * MB);   // 2 MB
    __hip_bfloat16* Wt1    = (__hip_bfloat16*)(w + 32 * MB);   // 8 MB  [4096][1024]
    __hip_bfloat16* Wt2    = (__hip_bfloat16*)(w + 40 * MB);   // 8 MB  [1024][4096]
    float*          BiasQKVs = (float*)(w + 48 * MB);          // 12 KB
    float*          BiasKVc  = (float*)(w + 48 * MB + 65536);  // 8 KB
    __hip_bfloat16* QKV    = (__hip_bfloat16*)(w + 49 * MB);   // 24 MB
    __hip_bfloat16* Qc     = QKV;                               // 8 MB [4096][1024]
    __hip_bfloat16* KVc    = (__hip_bfloat16*)(w + 57 * MB);   // 16 MB [4096][2048]
    __hip_bfloat16* VtBuf  = (__hip_bfloat16*)(w + 73 * MB);   // 8 MB [2048][2048]
    __hip_bfloat16* Attn   = (__hip_bfloat16*)(w + 81 * MB);   // 8 MB
    float*          X1f    = (float*)(w + 97 * MB);            // 16 MB (resid for LN2)
    __hip_bfloat16* X1b    = (__hip_bfloat16*)(w + 113 * MB);  // 8 MB
    float*          X2f    = (float*)(w + 121 * MB);           // 16 MB
    __hip_bfloat16* X2b    = (__hip_bfloat16*)(w + 137 * MB);  // 8 MB
    __hip_bfloat16* H1     = (__hip_bfloat16*)(w + 145 * MB);  // 32 MB (FFN; scratch below)
    float*          FaO    = (float*)(w + 145 * MB);           // 16 MB self-flash partial O (dead before FFN)
    float*          FaL    = (float*)(w + 161 * MB);           // 256 KB self-flash partial l
    // bf16 split-K partials, 8 MB each. Liveness: P0/P1 during Wo GEMM->LN only
    // (overlaps dead Qc/KVc regions at those points); P0..P3 for FFN2 overlap
    // dead QKV/KVc/VtBuf.
    __hip_bfloat16* P0b    = (__hip_bfloat16*)(w + 49 * MB);
    __hip_bfloat16* P1b    = (__hip_bfloat16*)(w + 57 * MB);
    __hip_bfloat16* P2b    = (__hip_bfloat16*)(w + 65 * MB);
    __hip_bfloat16* P3b    = (__hip_bfloat16*)(w + 73 * MB);
    const int NOVT = 1 << 30;

    // ---- prep (1 launch: casts + all weight transposes + bias concats) ----
    prep_all_k<<<24596, 256, 0, stream>>>(dec, enc, Xdec, Xenc,
                                          Wq_s, Wk_s, Wv_s, Wq_c, Wk_c, Wv_c, Wo_s, Wo_c,
                                          W1, W2, bq_s, bk_s, bv_s, bk_c, bv_c,
                                          WtQKVs, WtQc, WtKVc, WtOs, WtOc, Wt1, Wt2,
                                          BiasQKVs, BiasKVc);

    // ---- self attention ----
    gemm_bf16_k<<<dim3(24, 32), 256, 0, stream>>>(Xdec, WtQKVs, BiasQKVs, QKV, 3072, 1024, 0,
                                                  VtBuf, 2048);
    flash_attn<<<dim3(48, 32), 256, 0, stream>>>(QKV, 3072, 0, QKV, 3072, 1024, VtBuf, Attn, 1,
                                                 FaO, FaL);
    fa_combine_k<<<512, 256, 0, stream>>>(FaO, FaL, Attn);
    gemm_sk2_k<<<dim3(8, 32, 2), 256, 0, stream>>>(Attn, WtOs, P0b, 1024, 1024);
    ln2_k<<<MROWS, 256, 0, stream>>>(dec, P0b, P1b, bo_s, g1, be1, X1f, X1b);

    // ---- cross attention ----
    gemm_pair_k<<<dim3(24, 32), 256, 0, stream>>>(X1b, WtQc, bq_c, Qc, 1024, 1024,
                                                  Xenc, WtKVc, BiasKVc, KVc, 2048, 1024,
                                                  VtBuf, 1024, 8);
    flash_attn<<<dim3(32, 32), 256, 0, stream>>>(Qc, 1024, 0, KVc, 2048, 0, VtBuf, Attn, 0,
                                                 nullptr, nullptr);
    gemm_sk2_k<<<dim3(8, 32, 2), 256, 0, stream>>>(Attn, WtOc, P0b, 1024, 1024);
    ln2_k<<<MROWS, 256, 0, stream>>>(X1f, P0b, P1b, bo_c, g2, be2, X2f, X2b);

    // ---- FFN ----
    g256_k<<<dim3(16, 16), 512, 0, stream>>>(X2b, Wt1, b1, H1, 4096, 1024, 1,
                                             nullptr, NOVT);
    g256_sk4_k<<<dim3(4, 16, 4), 512, 0, stream>>>(H1, Wt2, P0b, P1b, P2b, P3b, 1024, 4096);
    ln4_k<<<MROWS, 256, 0, stream>>>(X2f, P0b, P1b, P2b, P3b, b2, g3, be3, (float*)d_out);
}